// Round 1
// baseline (1699.267 us; speedup 1.0000x reference)
//
#include <hip/hip_runtime.h>
#include <hip/hip_bf16.h>
#include <math.h>

constexpr int L = 4, D = 512, H = 8, DFF = 2048, T = 256, B = 8, BUCKETS = 32;
constexpr int DH = D / H;          // 64
constexpr int NT = B * T;          // 2048 rows

// ---------------------------------------------------------------------------
// embed: x[b,t,d] = src[t,b,d]*sqrt(D) + pe[t,d]
// ---------------------------------------------------------------------------
__global__ __launch_bounds__(256) void embed_kernel(const float* __restrict__ src,
                                                    float* __restrict__ x)
{
    int idx = blockIdx.x * 256 + threadIdx.x;        // over B*T*D = 1M
    int d = idx & (D - 1);
    int t = (idx >> 9) & (T - 1);
    int b = idx >> 17;
    int i = d >> 1;
    float div = expf(-(float)(2 * i) * (9.210340371976184f / (float)D)); // ln(10000)
    float ang = (float)t * div;
    float pe = (d & 1) ? cosf(ang) : sinf(ang);
    x[idx] = src[((size_t)t * B + b) * D + d] * 22.62741699796952f + pe; // sqrt(512)
}

// ---------------------------------------------------------------------------
// LayerNorm: row-wise over D=512, 256 threads x 2 elems
// ---------------------------------------------------------------------------
__device__ __forceinline__ void ln_core(const float* __restrict__ xr,
                                        const float* __restrict__ g,
                                        const float* __restrict__ bb,
                                        float* o0, float* o1, int tid)
{
    float v0 = xr[tid], v1 = xr[tid + 256];
    float s = v0 + v1, q2 = v0 * v0 + v1 * v1;
#pragma unroll
    for (int o = 32; o; o >>= 1) { s += __shfl_xor(s, o); q2 += __shfl_xor(q2, o); }
    __shared__ float rs[4], rq[4];
    int lane = tid & 63, wid = tid >> 6;
    if (lane == 0) { rs[wid] = s; rq[wid] = q2; }
    __syncthreads();
    s = rs[0] + rs[1] + rs[2] + rs[3];
    q2 = rq[0] + rq[1] + rq[2] + rq[3];
    float mean = s * (1.f / (float)D);
    float var = q2 * (1.f / (float)D) - mean * mean;
    float rstd = rsqrtf(var + 1e-6f);
    *o0 = (v0 - mean) * rstd * g[tid] + bb[tid];
    *o1 = (v1 - mean) * rstd * g[tid + 256] + bb[tid + 256];
}

__global__ __launch_bounds__(256) void ln_kernel(const float* __restrict__ x,
                                                 float* __restrict__ y,
                                                 const float* __restrict__ g,
                                                 const float* __restrict__ bb)
{
    int row = blockIdx.x, tid = threadIdx.x;
    float o0, o1;
    ln_core(x + (size_t)row * D, g, bb, &o0, &o1, tid);
    y[(size_t)row * D + tid] = o0;
    y[(size_t)row * D + tid + 256] = o1;
}

__global__ __launch_bounds__(256) void final_ln_kernel(const float* __restrict__ x,
                                                       float* __restrict__ out,
                                                       const float* __restrict__ g,
                                                       const float* __restrict__ bb)
{
    int row = blockIdx.x, tid = threadIdx.x;   // row = b*T + t
    int b = row >> 8, t = row & (T - 1);
    float o0, o1;
    ln_core(x + (size_t)row * D, g, bb, &o0, &o1, tid);
    float* op = out + ((size_t)t * B + b) * D; // (T,B,D)
    op[tid] = o0;
    op[tid + 256] = o1;
}

// ---------------------------------------------------------------------------
// Generic GEMM: C[n,m] = (sum_k A[n,k] * W[m,k] + bias[m]) * scale  (+relu)(+resid)
// A: (N,K) row-major, W: (M,K) row-major, C/resid: (N,M) row-major
// 64x64 tile, K-step 16, 256 threads, 4x4 per thread
// ---------------------------------------------------------------------------
template <bool RELU, bool RESID>
__global__ __launch_bounds__(256) void gemm_kernel(const float* __restrict__ A,
                                                   const float* __restrict__ W,
                                                   const float* __restrict__ bias,
                                                   const float* __restrict__ resid,
                                                   float* __restrict__ C,
                                                   int N, int M, int K, float scale)
{
    __shared__ float As[16][68];
    __shared__ float Ws[16][68];
    int bm = blockIdx.x * 64, bn = blockIdx.y * 64;
    int tid = threadIdx.x;
    int lr = tid >> 2;            // 0..63 (tile row)
    int lk = (tid & 3) * 4;       // 0,4,8,12
    int tr = (tid >> 4) * 4, tc = (tid & 15) * 4;
    float acc[4][4] = {};
    for (int k0 = 0; k0 < K; k0 += 16) {
        float4 a4 = *(const float4*)(A + (size_t)(bn + lr) * K + k0 + lk);
        float4 w4 = *(const float4*)(W + (size_t)(bm + lr) * K + k0 + lk);
        As[lk + 0][lr] = a4.x; As[lk + 1][lr] = a4.y; As[lk + 2][lr] = a4.z; As[lk + 3][lr] = a4.w;
        Ws[lk + 0][lr] = w4.x; Ws[lk + 1][lr] = w4.y; Ws[lk + 2][lr] = w4.z; Ws[lk + 3][lr] = w4.w;
        __syncthreads();
#pragma unroll
        for (int kk = 0; kk < 16; kk++) {
            float4 av = *(const float4*)&As[kk][tr];
            float4 wv = *(const float4*)&Ws[kk][tc];
            float aa[4] = {av.x, av.y, av.z, av.w};
            float ww[4] = {wv.x, wv.y, wv.z, wv.w};
#pragma unroll
            for (int i = 0; i < 4; i++)
#pragma unroll
                for (int j = 0; j < 4; j++) acc[i][j] += aa[i] * ww[j];
        }
        __syncthreads();
    }
#pragma unroll
    for (int i = 0; i < 4; i++) {
        int n = bn + tr + i;
#pragma unroll
        for (int j = 0; j < 4; j++) {
            int m = bm + tc + j;
            float val = (acc[i][j] + bias[m]) * scale;
            if (RELU) val = fmaxf(val, 0.f);
            if (RESID) val += resid[(size_t)n * M + m];
            C[(size_t)n * M + m] = val;
        }
    }
}

// ---------------------------------------------------------------------------
// qrel[b,h,qi,bucket] = sum_d (q[b,qi,h*DH+d] + v[h*DH+d]) * rel[bucket*D + h*DH + d]
// grid = B*T blocks
// ---------------------------------------------------------------------------
__global__ __launch_bounds__(256) void qrel_kernel(const float* __restrict__ q,
                                                   const float* __restrict__ vvec,
                                                   const float* __restrict__ rel,
                                                   float* __restrict__ qrel)
{
    int bq = blockIdx.x;
    int b = bq >> 8, qi = bq & (T - 1);
    int tid = threadIdx.x;
    __shared__ float qv[D];
    const float* qp = q + (size_t)(b * T + qi) * D;
    qv[tid] = qp[tid] + vvec[tid];
    qv[tid + 256] = qp[tid + 256] + vvec[tid + 256];
    __syncthreads();
    for (int item = tid; item < H * (BUCKETS + 1); item += 256) {
        int h = item / (BUCKETS + 1);
        int bu = item % (BUCKETS + 1);
        const float* rp = rel + (size_t)bu * D + h * DH;
        const float* qh = &qv[h * DH];
        float s = 0.f;
#pragma unroll
        for (int d = 0; d < DH; d++) s += qh[d] * rp[d];
        qrel[((size_t)(b * H + h) * T + qi) * (BUCKETS + 1) + bu] = s;
    }
}

// ---------------------------------------------------------------------------
// Fused scores + rel-gather + mask + softmax.
// grid (B*H, T/64); 256 threads = one per key ki; 64 query rows per block.
// attn[(b*H+h)*T + qi][ki]
// ---------------------------------------------------------------------------
__global__ __launch_bounds__(256) void attn_kernel(const float* __restrict__ q,
                                                   const float* __restrict__ kbuf,
                                                   const float* __restrict__ u,
                                                   const float* __restrict__ qrel,
                                                   const int* __restrict__ dist,
                                                   const int* __restrict__ lengths,
                                                   float* __restrict__ attn)
{
    int bh = blockIdx.x, b = bh >> 3, h = bh & 7;
    int qi0 = blockIdx.y * 64;
    int tid = threadIdx.x;                 // = ki
    __shared__ float quS[64][68];
    __shared__ float qrelS[64][BUCKETS + 1];
    __shared__ float redm[4], reds[4];

    // k row -> registers (64 floats)
    float kreg[64];
    {
        const float* kp = kbuf + (size_t)(b * T + tid) * D + h * DH;
#pragma unroll
        for (int i = 0; i < 16; i++) {
            float4 t4 = *(const float4*)(kp + 4 * i);
            kreg[4 * i + 0] = t4.x; kreg[4 * i + 1] = t4.y;
            kreg[4 * i + 2] = t4.z; kreg[4 * i + 3] = t4.w;
        }
    }
    // (q+u) rows for the 64 qi of this block
#pragma unroll
    for (int c0 = 0; c0 < 4; c0++) {
        int c = tid + c0 * 256;            // f4 chunk 0..1023
        int qi = c >> 4, dc = (c & 15) * 4;
        float4 qv = *(const float4*)(q + (size_t)(b * T + qi0 + qi) * D + h * DH + dc);
        float4 uv = *(const float4*)(u + h * DH + dc);
        quS[qi][dc + 0] = qv.x + uv.x; quS[qi][dc + 1] = qv.y + uv.y;
        quS[qi][dc + 2] = qv.z + uv.z; quS[qi][dc + 3] = qv.w + uv.w;
    }
    for (int c = tid; c < 64 * (BUCKETS + 1); c += 256) {
        int qi = c / (BUCKETS + 1), bu = c % (BUCKETS + 1);
        qrelS[qi][bu] = qrel[((size_t)bh * T + qi0 + qi) * (BUCKETS + 1) + bu];
    }
    __syncthreads();

    int len = lengths[b];
    bool masked = (tid >= len);
    int lane = tid & 63, wid = tid >> 6;
    const int* dp = dist + (size_t)b * T * T + (size_t)qi0 * T + tid;
    float* op = attn + ((size_t)bh * T + qi0) * T + tid;

    for (int qi = 0; qi < 64; qi++) {
        float s = 0.f;
#pragma unroll
        for (int i = 0; i < 16; i++) {
            float4 a = *(const float4*)&quS[qi][4 * i];
            s += a.x * kreg[4 * i] + a.y * kreg[4 * i + 1] +
                 a.z * kreg[4 * i + 2] + a.w * kreg[4 * i + 3];
        }
        int dv = dp[(size_t)qi * T];
        s += qrelS[qi][dv];
        if (masked) s = -1e30f;
        // block-wide softmax over the 256 keys
        float m = s;
#pragma unroll
        for (int o = 32; o; o >>= 1) m = fmaxf(m, __shfl_xor(m, o));
        if (lane == 0) redm[wid] = m;
        __syncthreads();
        m = fmaxf(fmaxf(redm[0], redm[1]), fmaxf(redm[2], redm[3]));
        float e = masked ? 0.f : expf(s - m);
        float se = e;
#pragma unroll
        for (int o = 32; o; o >>= 1) se += __shfl_xor(se, o);
        if (lane == 0) reds[wid] = se;
        __syncthreads();
        float sum = reds[0] + reds[1] + reds[2] + reds[3];
        op[(size_t)qi * T] = e / sum;
    }
}

// ---------------------------------------------------------------------------
// ctx = attn @ v  per (b,h): (256x256)@(256x64); grid (1, T/64, B*H)
// B operand is (K,M) row-major with ldb = D.
// ---------------------------------------------------------------------------
__global__ __launch_bounds__(256) void attnv_kernel(const float* __restrict__ attn,
                                                    const float* __restrict__ v,
                                                    float* __restrict__ ctx)
{
    int bh = blockIdx.z, b = bh >> 3, h = bh & 7;
    const float* A = attn + (size_t)bh * T * T;
    const float* Bv = v + (size_t)(b * T) * D + h * DH;
    float* C = ctx + (size_t)(b * T) * D + h * DH;
    int bn = blockIdx.y * 64;
    int tid = threadIdx.x;
    __shared__ float As[16][68], Bs[16][68];
    int lr = tid >> 2, lk = (tid & 3) * 4;     // A tile: 64 rows x 16 k
    int bkk = tid >> 4, bcol = (tid & 15) * 4; // B tile: 16 k x 64 cols
    int tr = (tid >> 4) * 4, tc = (tid & 15) * 4;
    float acc[4][4] = {};
    for (int k0 = 0; k0 < T; k0 += 16) {
        float4 a4 = *(const float4*)(A + (size_t)(bn + lr) * T + k0 + lk);
        As[lk + 0][lr] = a4.x; As[lk + 1][lr] = a4.y; As[lk + 2][lr] = a4.z; As[lk + 3][lr] = a4.w;
        float4 b4 = *(const float4*)(Bv + (size_t)(k0 + bkk) * D + bcol);
        *(float4*)&Bs[bkk][bcol] = b4;
        __syncthreads();
#pragma unroll
        for (int kk = 0; kk < 16; kk++) {
            float4 av = *(const float4*)&As[kk][tr];
            float4 wv = *(const float4*)&Bs[kk][tc];
            float aa[4] = {av.x, av.y, av.z, av.w};
            float ww[4] = {wv.x, wv.y, wv.z, wv.w};
#pragma unroll
            for (int i = 0; i < 4; i++)
#pragma unroll
                for (int j = 0; j < 4; j++) acc[i][j] += aa[i] * ww[j];
        }
        __syncthreads();
    }
#pragma unroll
    for (int i = 0; i < 4; i++)
#pragma unroll
        for (int j = 0; j < 4; j++)
            C[(size_t)(bn + tr + i) * D + tc + j] = acc[i][j];
}

// ---------------------------------------------------------------------------
extern "C" void kernel_launch(void* const* d_in, const int* in_sizes, int n_in,
                              void* d_out, int out_size, void* d_ws, size_t ws_size,
                              hipStream_t stream)
{
    const float* src     = (const float*)d_in[0];
    const int*   lengths = (const int*)d_in[1];
    const int*   dist    = (const int*)d_in[2];
    const float* u       = (const float*)d_in[3];
    const float* v       = (const float*)d_in[4];
    const float* ln1_g   = (const float*)d_in[5];
    const float* ln1_b   = (const float*)d_in[6];
    const float* Wq      = (const float*)d_in[7];
    const float* Wk      = (const float*)d_in[8];
    const float* Wv      = (const float*)d_in[9];
    const float* Wo      = (const float*)d_in[10];
    const float* bq      = (const float*)d_in[11];
    const float* bk      = (const float*)d_in[12];
    const float* bv      = (const float*)d_in[13];
    const float* bo      = (const float*)d_in[14];
    const float* rel     = (const float*)d_in[15];
    const float* fg      = (const float*)d_in[16];
    const float* fb      = (const float*)d_in[17];
    const float* W1      = (const float*)d_in[18];
    const float* b1      = (const float*)d_in[19];
    const float* W2      = (const float*)d_in[20];
    const float* b2      = (const float*)d_in[21];
    const float* flg     = (const float*)d_in[22];
    const float* flb     = (const float*)d_in[23];

    float* ws = (float*)d_ws;
    const size_t M1 = (size_t)1 << 20;        // NT*D floats
    float* X    = ws;
    float* Hb   = ws + M1;
    float* Qb   = ws + 2 * M1;
    float* Kb   = ws + 3 * M1;
    float* Vb   = ws + 4 * M1;
    float* ATT  = ws + 5 * M1;                // 4M floats (also FFN intermediate)
    float* QREL = ws + 9 * M1;                // B*H*T*33 = 540672 floats

    embed_kernel<<<4096, 256, 0, stream>>>(src, X);

    for (int l = 0; l < L; l++) {
        const float* wq = Wq + (size_t)l * D * D;
        const float* wk = Wk + (size_t)l * D * D;
        const float* wv = Wv + (size_t)l * D * D;
        const float* wo = Wo + (size_t)l * D * D;

        ln_kernel<<<NT, 256, 0, stream>>>(X, Hb, ln1_g + l * D, ln1_b + l * D);

        gemm_kernel<false, false><<<dim3(8, 32), 256, 0, stream>>>(
            Hb, wq, bq + l * D, nullptr, Qb, NT, D, D, 0.125f);   // 1/sqrt(DH)
        gemm_kernel<false, false><<<dim3(8, 32), 256, 0, stream>>>(
            Hb, wk, bk + l * D, nullptr, Kb, NT, D, D, 1.f);
        gemm_kernel<false, false><<<dim3(8, 32), 256, 0, stream>>>(
            Hb, wv, bv + l * D, nullptr, Vb, NT, D, D, 1.f);

        qrel_kernel<<<NT, 256, 0, stream>>>(Qb, v, rel + (size_t)l * (BUCKETS + 1) * D, QREL);

        attn_kernel<<<dim3(B * H, T / 64), 256, 0, stream>>>(
            Qb, Kb, u, QREL, dist, lengths, ATT);

        attnv_kernel<<<dim3(1, T / 64, B * H), 256, 0, stream>>>(ATT, Vb, Hb); // ctx -> Hb

        gemm_kernel<false, true><<<dim3(8, 32), 256, 0, stream>>>(
            Hb, wo, bo + l * D, X, X, NT, D, D, 1.f);             // + residual, in-place

        ln_kernel<<<NT, 256, 0, stream>>>(X, Hb, fg + l * D, fb + l * D);

        gemm_kernel<true, false><<<dim3(32, 32), 256, 0, stream>>>(
            Hb, W1 + (size_t)l * DFF * D, b1 + l * DFF, nullptr, ATT, NT, DFF, D, 1.f);

        gemm_kernel<false, true><<<dim3(8, 32), 256, 0, stream>>>(
            ATT, W2 + (size_t)l * D * DFF, b2 + l * D, X, X, NT, D, DFF, 1.f);
    }

    final_ln_kernel<<<NT, 256, 0, stream>>>(X, (float*)d_out, flg, flb);
}

// Round 2
// 936.691 us; speedup vs baseline: 1.8141x; 1.8141x over previous
//
#include <hip/hip_runtime.h>
#include <hip/hip_bf16.h>
#include <math.h>

constexpr int L = 4, D = 512, H = 8, DFF = 2048, T = 256, B = 8, BUCKETS = 32;
constexpr int DH = D / H;          // 64
constexpr int NT = B * T;          // 2048 rows
constexpr int QKVLD = 3 * D;       // 1536

typedef __attribute__((ext_vector_type(8))) short bf16x8;
typedef __attribute__((ext_vector_type(4))) float f32x4;

__device__ __forceinline__ unsigned short f2bf(float f) {
    unsigned int x = __float_as_uint(f);
    return (unsigned short)((x + 0x7fffu + ((x >> 16) & 1u)) >> 16);
}

__device__ __forceinline__ void stage16(const unsigned short* g, short* l) {
    __builtin_amdgcn_global_load_lds((const __attribute__((address_space(1))) unsigned int*)g,
                                     (__attribute__((address_space(3))) unsigned int*)l,
                                     16, 0, 0);
}

// ---------------------------------------------------------------------------
// embed: x[b,t,d] = src[t,b,d]*sqrt(D) + pe[t,d]
// ---------------------------------------------------------------------------
__global__ __launch_bounds__(256) void embed_kernel(const float* __restrict__ src,
                                                    float* __restrict__ x)
{
    int idx = blockIdx.x * 256 + threadIdx.x;        // over B*T*D = 1M
    int d = idx & (D - 1);
    int t = (idx >> 9) & (T - 1);
    int b = idx >> 17;
    int i = d >> 1;
    float div = expf(-(float)(2 * i) * (9.210340371976184f / (float)D)); // ln(10000)
    float ang = (float)t * div;
    float pe = (d & 1) ? cosf(ang) : sinf(ang);
    x[idx] = src[((size_t)t * B + b) * D + d] * 22.62741699796952f + pe; // sqrt(512)
}

// ---------------------------------------------------------------------------
// LayerNorm over D=512; writes bf16 (feeds MFMA GEMMs)
// ---------------------------------------------------------------------------
__device__ __forceinline__ void ln_core(const float* __restrict__ xr,
                                        const float* __restrict__ g,
                                        const float* __restrict__ bb,
                                        float* o0, float* o1, int tid)
{
    float v0 = xr[tid], v1 = xr[tid + 256];
    float s = v0 + v1, q2 = v0 * v0 + v1 * v1;
#pragma unroll
    for (int o = 32; o; o >>= 1) { s += __shfl_xor(s, o); q2 += __shfl_xor(q2, o); }
    __shared__ float rs[4], rq[4];
    int lane = tid & 63, wid = tid >> 6;
    if (lane == 0) { rs[wid] = s; rq[wid] = q2; }
    __syncthreads();
    s = rs[0] + rs[1] + rs[2] + rs[3];
    q2 = rq[0] + rq[1] + rq[2] + rq[3];
    float mean = s * (1.f / (float)D);
    float var = q2 * (1.f / (float)D) - mean * mean;
    float rstd = rsqrtf(var + 1e-6f);
    *o0 = (v0 - mean) * rstd * g[tid] + bb[tid];
    *o1 = (v1 - mean) * rstd * g[tid + 256] + bb[tid + 256];
}

__global__ __launch_bounds__(256) void ln_kernel(const float* __restrict__ x,
                                                 unsigned short* __restrict__ y,
                                                 const float* __restrict__ g,
                                                 const float* __restrict__ bb)
{
    int row = blockIdx.x, tid = threadIdx.x;
    float o0, o1;
    ln_core(x + (size_t)row * D, g, bb, &o0, &o1, tid);
    y[(size_t)row * D + tid] = f2bf(o0);
    y[(size_t)row * D + tid + 256] = f2bf(o1);
}

__global__ __launch_bounds__(256) void final_ln_kernel(const float* __restrict__ x,
                                                       float* __restrict__ out,
                                                       const float* __restrict__ g,
                                                       const float* __restrict__ bb)
{
    int row = blockIdx.x, tid = threadIdx.x;   // row = b*T + t
    int b = row >> 8, t = row & (T - 1);
    float o0, o1;
    ln_core(x + (size_t)row * D, g, bb, &o0, &o1, tid);
    float* op = out + ((size_t)t * B + b) * D; // (T,B,D)
    op[tid] = o0;
    op[tid + 256] = o1;
}

// ---------------------------------------------------------------------------
// per-layer weight f32->bf16 conversion (+ QKV weight/bias concat)
// grid: 1536 blocks x 256 (393216 groups of 8 elems)
// ---------------------------------------------------------------------------
__global__ __launch_bounds__(256) void convert_layer_kernel(
    const float* __restrict__ Wq, const float* __restrict__ Wk, const float* __restrict__ Wv,
    const float* __restrict__ Wo, const float* __restrict__ W1, const float* __restrict__ W2,
    const float* __restrict__ bq, const float* __restrict__ bk, const float* __restrict__ bv,
    int l,
    unsigned short* __restrict__ WQKVb, unsigned short* __restrict__ Wob,
    unsigned short* __restrict__ W1b, unsigned short* __restrict__ W2b,
    float* __restrict__ bqkv)
{
    int g = blockIdx.x * 256 + threadIdx.x;   // 0 .. 393215
    const float* src; unsigned short* dst;
    if (g < 98304) {
        int e = g * 8; int piece = e >> 18; int rem = e & 262143;
        src = (piece == 0 ? Wq : piece == 1 ? Wk : Wv) + (size_t)l * 262144 + rem;
        dst = WQKVb + e;
    } else if (g < 131072) {
        int e = (g - 98304) * 8;
        src = Wo + (size_t)l * 262144 + e; dst = Wob + e;
    } else if (g < 262144) {
        int e = (g - 131072) * 8;
        src = W1 + (size_t)l * 1048576 + e; dst = W1b + e;
    } else {
        int e = (g - 262144) * 8;
        src = W2 + (size_t)l * 1048576 + e; dst = W2b + e;
    }
    float4 x = *(const float4*)src, y = *(const float4*)(src + 4);
    uint4 o;
    o.x = (unsigned)f2bf(x.x) | ((unsigned)f2bf(x.y) << 16);
    o.y = (unsigned)f2bf(x.z) | ((unsigned)f2bf(x.w) << 16);
    o.z = (unsigned)f2bf(y.x) | ((unsigned)f2bf(y.y) << 16);
    o.w = (unsigned)f2bf(y.z) | ((unsigned)f2bf(y.w) << 16);
    *(uint4*)dst = o;
    if (g < 3 * D) {
        int piece = g >> 9, r2 = g & 511;
        bqkv[g] = (piece == 0 ? bq : piece == 1 ? bk : bv)[l * 512 + r2];
    }
}

// ---------------------------------------------------------------------------
// bf16 MFMA GEMM: C[n,m] = sum_k A[n,k]*W[m,k] + bias[m] (+relu)(+resid)
// A (N,K) bf16 row-major, W (M,K) bf16 row-major. 128x128 tile, BK=32,
// 256 thr = 4 waves (2x2), each wave 64x64 = 4x4 frags of 16x16x32 MFMA.
// LDS double-buffered; XOR chunk swizzle (chunk ^= (row>>1)&3) applied on
// the global SOURCE during global_load_lds (linear dest) and on ds_read.
// ---------------------------------------------------------------------------
template <bool RELU, bool RESID, bool OUTBF16>
__global__ __launch_bounds__(256) void mgemm_kernel(
    const unsigned short* __restrict__ A,
    const unsigned short* __restrict__ W,
    const float* __restrict__ bias,
    const float* __restrict__ resid,
    void* __restrict__ Cv,
    int N, int M, int K)
{
    __shared__ short smA[2][128 * 32];
    __shared__ short smB[2][128 * 32];
    int tid = threadIdx.x;
    int bn = blockIdx.y * 128;   // output rows
    int bm = blockIdx.x * 128;   // output cols
    const unsigned short* Ab = A + (size_t)bn * K;
    const unsigned short* Wb = W + (size_t)bm * K;

    f32x4 acc[4][4];
#pragma unroll
    for (int i = 0; i < 4; i++)
#pragma unroll
        for (int j = 0; j < 4; j++) acc[i][j] = (f32x4){0.f, 0.f, 0.f, 0.f};

    // staging: 512 chunks of 16B per tile, 2 per thread; physical slot
    // (row, p) holds logical chunk p ^ ((row>>1)&3)
    const int c0 = tid, c1 = tid + 256;
    const int r0 = c0 >> 2, p0 = c0 & 3, l0 = p0 ^ ((r0 >> 1) & 3);
    const int r1 = c1 >> 2, p1 = c1 & 3, l1 = p1 ^ ((r1 >> 1) & 3);

    auto stage = [&](int buf, int k0) {
        stage16(Ab + (size_t)r0 * K + k0 + l0 * 8, &smA[buf][c0 * 8]);
        stage16(Ab + (size_t)r1 * K + k0 + l1 * 8, &smA[buf][c1 * 8]);
        stage16(Wb + (size_t)r0 * K + k0 + l0 * 8, &smB[buf][c0 * 8]);
        stage16(Wb + (size_t)r1 * K + k0 + l1 * 8, &smB[buf][c1 * 8]);
    };

    const int lane = tid & 63;
    const int wv = tid >> 6, wr = wv >> 1, wc = wv & 1;
    int aoff[4], boff[4];
#pragma unroll
    for (int i = 0; i < 4; i++) {
        int ra = wr * 64 + i * 16 + (lane & 15);
        int ca = (lane >> 4) ^ ((ra >> 1) & 3);
        aoff[i] = ra * 32 + ca * 8;
        int rb = wc * 64 + i * 16 + (lane & 15);
        int cb = (lane >> 4) ^ ((rb >> 1) & 3);
        boff[i] = rb * 32 + cb * 8;
    }

    stage(0, 0);
    const int nkt = K >> 5;
    for (int kt = 0; kt < nkt; ++kt) {
        __syncthreads();
        int cur = kt & 1;
        if (kt + 1 < nkt) stage(cur ^ 1, (kt + 1) << 5);
        const short* sa = smA[cur];
        const short* sb = smB[cur];
        bf16x8 af[4], bfr[4];
#pragma unroll
        for (int i = 0; i < 4; i++) af[i] = *(const bf16x8*)(sa + aoff[i]);
#pragma unroll
        for (int j = 0; j < 4; j++) bfr[j] = *(const bf16x8*)(sb + boff[j]);
#pragma unroll
        for (int i = 0; i < 4; i++)
#pragma unroll
            for (int j = 0; j < 4; j++)
                acc[i][j] = __builtin_amdgcn_mfma_f32_16x16x32_bf16(af[i], bfr[j], acc[i][j], 0, 0, 0);
    }

    // epilogue: C/D layout col=lane&15, row=(lane>>4)*4+reg
#pragma unroll
    for (int j = 0; j < 4; j++) {
        int col = bm + wc * 64 + j * 16 + (lane & 15);
        float bval = bias[col];
#pragma unroll
        for (int i = 0; i < 4; i++) {
            f32x4 v = acc[i][j];
#pragma unroll
            for (int r = 0; r < 4; r++) {
                int row = bn + wr * 64 + i * 16 + (lane >> 4) * 4 + r;
                float val = v[r] + bval;
                if (RELU) val = fmaxf(val, 0.f);
                if (RESID) val += resid[(size_t)row * M + col];
                if (OUTBF16) ((unsigned short*)Cv)[(size_t)row * M + col] = f2bf(val);
                else         ((float*)Cv)[(size_t)row * M + col] = val;
            }
        }
    }
}

// ---------------------------------------------------------------------------
// qrel[b,h,qi,bucket] = sum_d (q*0.125 + v) * rel ; q from QKV buf (ld 1536)
// ---------------------------------------------------------------------------
__global__ __launch_bounds__(256) void qrel_kernel(const float* __restrict__ qkv,
                                                   const float* __restrict__ vvec,
                                                   const float* __restrict__ rel,
                                                   float* __restrict__ qrel)
{
    int bq = blockIdx.x;
    int b = bq >> 8, qi = bq & (T - 1);
    int tid = threadIdx.x;
    __shared__ float qv[D];
    const float* qp = qkv + (size_t)(b * T + qi) * QKVLD;
    qv[tid] = qp[tid] * 0.125f + vvec[tid];
    qv[tid + 256] = qp[tid + 256] * 0.125f + vvec[tid + 256];
    __syncthreads();
    for (int item = tid; item < H * (BUCKETS + 1); item += 256) {
        int h = item / (BUCKETS + 1);
        int bu = item % (BUCKETS + 1);
        const float* rp = rel + (size_t)bu * D + h * DH;
        const float* qh = &qv[h * DH];
        float s = 0.f;
#pragma unroll
        for (int d = 0; d < DH; d++) s += qh[d] * rp[d];
        qrel[((size_t)(b * H + h) * T + qi) * (BUCKETS + 1) + bu] = s;
    }
}

// ---------------------------------------------------------------------------
// Fused scores + rel-gather + mask + softmax. Q,K from QKV buf (ld 1536).
// ---------------------------------------------------------------------------
__global__ __launch_bounds__(256) void attn_kernel(const float* __restrict__ qkv,
                                                   const float* __restrict__ u,
                                                   const float* __restrict__ qrel,
                                                   const int* __restrict__ dist,
                                                   const int* __restrict__ lengths,
                                                   float* __restrict__ attn)
{
    int bh = blockIdx.x, b = bh >> 3, h = bh & 7;
    int qi0 = blockIdx.y * 64;
    int tid = threadIdx.x;                 // = ki
    __shared__ float quS[64][68];
    __shared__ float qrelS[64][BUCKETS + 1];
    __shared__ float redm[4], reds[4];

    float kreg[64];
    {
        const float* kp = qkv + (size_t)(b * T + tid) * QKVLD + D + h * DH;
#pragma unroll
        for (int i = 0; i < 16; i++) {
            float4 t4 = *(const float4*)(kp + 4 * i);
            kreg[4 * i + 0] = t4.x; kreg[4 * i + 1] = t4.y;
            kreg[4 * i + 2] = t4.z; kreg[4 * i + 3] = t4.w;
        }
    }
#pragma unroll
    for (int c0 = 0; c0 < 4; c0++) {
        int c = tid + c0 * 256;            // f4 chunk 0..1023
        int qi = c >> 4, dc = (c & 15) * 4;
        float4 qv = *(const float4*)(qkv + (size_t)(b * T + qi0 + qi) * QKVLD + h * DH + dc);
        float4 uv = *(const float4*)(u + h * DH + dc);
        quS[qi][dc + 0] = qv.x * 0.125f + uv.x; quS[qi][dc + 1] = qv.y * 0.125f + uv.y;
        quS[qi][dc + 2] = qv.z * 0.125f + uv.z; quS[qi][dc + 3] = qv.w * 0.125f + uv.w;
    }
    for (int c = tid; c < 64 * (BUCKETS + 1); c += 256) {
        int qi = c / (BUCKETS + 1), bu = c % (BUCKETS + 1);
        qrelS[qi][bu] = qrel[((size_t)bh * T + qi0 + qi) * (BUCKETS + 1) + bu];
    }
    __syncthreads();

    int len = lengths[b];
    bool masked = (tid >= len);
    int lane = tid & 63, wid = tid >> 6;
    const int* dp = dist + (size_t)b * T * T + (size_t)qi0 * T + tid;
    float* op = attn + ((size_t)bh * T + qi0) * T + tid;

    for (int qi = 0; qi < 64; qi++) {
        float s = 0.f;
#pragma unroll
        for (int i = 0; i < 16; i++) {
            float4 a = *(const float4*)&quS[qi][4 * i];
            s += a.x * kreg[4 * i] + a.y * kreg[4 * i + 1] +
                 a.z * kreg[4 * i + 2] + a.w * kreg[4 * i + 3];
        }
        int dv = dp[(size_t)qi * T];
        s += qrelS[qi][dv];
        if (masked) s = -1e30f;
        float m = s;
#pragma unroll
        for (int o = 32; o; o >>= 1) m = fmaxf(m, __shfl_xor(m, o));
        if (lane == 0) redm[wid] = m;
        __syncthreads();
        m = fmaxf(fmaxf(redm[0], redm[1]), fmaxf(redm[2], redm[3]));
        float e = masked ? 0.f : expf(s - m);
        float se = e;
#pragma unroll
        for (int o = 32; o; o >>= 1) se += __shfl_xor(se, o);
        if (lane == 0) reds[wid] = se;
        __syncthreads();
        float sum = reds[0] + reds[1] + reds[2] + reds[3];
        op[(size_t)qi * T] = e / sum;
    }
}

// ---------------------------------------------------------------------------
// ctx = attn @ v  per (b,h); v from QKV buf (ld 1536); ctx written bf16
// ---------------------------------------------------------------------------
__global__ __launch_bounds__(256) void attnv_kernel(const float* __restrict__ attn,
                                                    const float* __restrict__ qkv,
                                                    unsigned short* __restrict__ ctx)
{
    int bh = blockIdx.z, b = bh >> 3, h = bh & 7;
    const float* A = attn + (size_t)bh * T * T;
    const float* Bv = qkv + (size_t)(b * T) * QKVLD + 2 * D + h * DH;
    unsigned short* C = ctx + (size_t)(b * T) * D + h * DH;
    int bn = blockIdx.y * 64;
    int tid = threadIdx.x;
    __shared__ float As[16][68], Bs[16][68];
    int lr = tid >> 2, lk = (tid & 3) * 4;
    int bkk = tid >> 4, bcol = (tid & 15) * 4;
    int tr = (tid >> 4) * 4, tc = (tid & 15) * 4;
    float acc[4][4] = {};
    for (int k0 = 0; k0 < T; k0 += 16) {
        float4 a4 = *(const float4*)(A + (size_t)(bn + lr) * T + k0 + lk);
        As[lk + 0][lr] = a4.x; As[lk + 1][lr] = a4.y; As[lk + 2][lr] = a4.z; As[lk + 3][lr] = a4.w;
        float4 b4 = *(const float4*)(Bv + (size_t)(k0 + bkk) * QKVLD + bcol);
        *(float4*)&Bs[bkk][bcol] = b4;
        __syncthreads();
#pragma unroll
        for (int kk = 0; kk < 16; kk++) {
            float4 av = *(const float4*)&As[kk][tr];
            float4 wv = *(const float4*)&Bs[kk][tc];
            float aa[4] = {av.x, av.y, av.z, av.w};
            float ww[4] = {wv.x, wv.y, wv.z, wv.w};
#pragma unroll
            for (int i = 0; i < 4; i++)
#pragma unroll
                for (int j = 0; j < 4; j++) acc[i][j] += aa[i] * ww[j];
        }
        __syncthreads();
    }
#pragma unroll
    for (int i = 0; i < 4; i++)
#pragma unroll
        for (int j = 0; j < 4; j++)
            C[(size_t)(bn + tr + i) * D + tc + j] = f2bf(acc[i][j]);
}

// ---------------------------------------------------------------------------
extern "C" void kernel_launch(void* const* d_in, const int* in_sizes, int n_in,
                              void* d_out, int out_size, void* d_ws, size_t ws_size,
                              hipStream_t stream)
{
    const float* src     = (const float*)d_in[0];
    const int*   lengths = (const int*)d_in[1];
    const int*   dist    = (const int*)d_in[2];
    const float* u       = (const float*)d_in[3];
    const float* v       = (const float*)d_in[4];
    const float* ln1_g   = (const float*)d_in[5];
    const float* ln1_b   = (const float*)d_in[6];
    const float* Wq      = (const float*)d_in[7];
    const float* Wk      = (const float*)d_in[8];
    const float* Wv      = (const float*)d_in[9];
    const float* Wo      = (const float*)d_in[10];
    const float* bq      = (const float*)d_in[11];
    const float* bk      = (const float*)d_in[12];
    const float* bv      = (const float*)d_in[13];
    const float* bo      = (const float*)d_in[14];
    const float* rel     = (const float*)d_in[15];
    const float* fg      = (const float*)d_in[16];
    const float* fb      = (const float*)d_in[17];
    const float* W1      = (const float*)d_in[18];
    const float* b1      = (const float*)d_in[19];
    const float* W2      = (const float*)d_in[20];
    const float* b2      = (const float*)d_in[21];
    const float* flg     = (const float*)d_in[22];
    const float* flb     = (const float*)d_in[23];

    float* ws = (float*)d_ws;
    float*          X     = ws;                                   // 1048576 f
    float*          QKV   = ws + 1048576;                         // 3145728 f
    float*          ATT   = ws + 4194304;                         // 4194304 f
    float*          QREL  = ws + 8388608;                         // 540672 f
    unsigned short* Hb    = (unsigned short*)(ws + 8929280);      // 1M bf16
    unsigned short* CTX   = (unsigned short*)(ws + 9453568);      // 1M bf16
    unsigned short* WQKVb = (unsigned short*)(ws + 9977856);      // 786432 bf16
    unsigned short* Wob   = (unsigned short*)(ws + 10371072);     // 262144 bf16
    unsigned short* W1b   = (unsigned short*)(ws + 10502144);     // 1048576 bf16
    unsigned short* W2b   = (unsigned short*)(ws + 11026432);     // 1048576 bf16
    float*          bqkv  = ws + 11550720;                        // 1536 f
    unsigned short* FF1   = (unsigned short*)ATT;                 // 4M bf16 (reuse)

    embed_kernel<<<4096, 256, 0, stream>>>(src, X);

    for (int l = 0; l < L; l++) {
        convert_layer_kernel<<<1536, 256, 0, stream>>>(
            Wq, Wk, Wv, Wo, W1, W2, bq, bk, bv, l, WQKVb, Wob, W1b, W2b, bqkv);

        ln_kernel<<<NT, 256, 0, stream>>>(X, Hb, ln1_g + l * D, ln1_b + l * D);

        // fused QKV: (2048 x 1536) = Hb (2048x512) @ WQKV^T
        mgemm_kernel<false, false, false><<<dim3(12, 16), 256, 0, stream>>>(
            Hb, WQKVb, bqkv, nullptr, QKV, NT, QKVLD, D);

        qrel_kernel<<<NT, 256, 0, stream>>>(QKV, v, rel + (size_t)l * (BUCKETS + 1) * D, QREL);

        attn_kernel<<<dim3(B * H, T / 64), 256, 0, stream>>>(
            QKV, u, QREL, dist, lengths, ATT);

        attnv_kernel<<<dim3(1, T / 64, B * H), 256, 0, stream>>>(ATT, QKV, CTX);

        mgemm_kernel<false, true, false><<<dim3(4, 16), 256, 0, stream>>>(
            CTX, Wob, bo + l * D, X, X, NT, D, D);

        ln_kernel<<<NT, 256, 0, stream>>>(X, Hb, fg + l * D, fb + l * D);

        mgemm_kernel<true, false, true><<<dim3(16, 16), 256, 0, stream>>>(
            Hb, W1b, b1 + l * DFF, nullptr, FF1, NT, DFF, D);

        mgemm_kernel<false, true, false><<<dim3(4, 16), 256, 0, stream>>>(
            FF1, W2b, b2 + l * D, X, X, NT, D, DFF);
    }

    final_ln_kernel<<<NT, 256, 0, stream>>>(X, (float*)d_out, flg, flb);
}

// Round 3
// 792.661 us; speedup vs baseline: 2.1438x; 1.1817x over previous
//
#include <hip/hip_runtime.h>
#include <hip/hip_bf16.h>
#include <math.h>

constexpr int L = 4, D = 512, H = 8, DFF = 2048, T = 256, B = 8, BUCKETS = 32;
constexpr int DH = D / H;          // 64
constexpr int NT = B * T;          // 2048 rows
constexpr int QKVLD = 3 * D;       // 1536

typedef __attribute__((ext_vector_type(8))) short bf16x8;
typedef __attribute__((ext_vector_type(4))) float f32x4;

__device__ __forceinline__ unsigned short f2bf(float f) {
    unsigned int x = __float_as_uint(f);
    return (unsigned short)((x + 0x7fffu + ((x >> 16) & 1u)) >> 16);
}
__device__ __forceinline__ float bf2f(unsigned short u) {
    return __uint_as_float((unsigned int)u << 16);
}

__device__ __forceinline__ void stage16(const unsigned short* g, short* l) {
    __builtin_amdgcn_global_load_lds((const __attribute__((address_space(1))) unsigned int*)g,
                                     (__attribute__((address_space(3))) unsigned int*)l,
                                     16, 0, 0);
}

// ---------------------------------------------------------------------------
// embed: x[b,t,d] = src[t,b,d]*sqrt(D) + pe[t,d]
// ---------------------------------------------------------------------------
__global__ __launch_bounds__(256) void embed_kernel(const float* __restrict__ src,
                                                    float* __restrict__ x)
{
    int idx = blockIdx.x * 256 + threadIdx.x;        // over B*T*D = 1M
    int d = idx & (D - 1);
    int t = (idx >> 9) & (T - 1);
    int b = idx >> 17;
    int i = d >> 1;
    float div = expf(-(float)(2 * i) * (9.210340371976184f / (float)D)); // ln(10000)
    float ang = (float)t * div;
    float pe = (d & 1) ? cosf(ang) : sinf(ang);
    x[idx] = src[((size_t)t * B + b) * D + d] * 22.62741699796952f + pe; // sqrt(512)
}

// ---------------------------------------------------------------------------
// LayerNorm over D=512; writes bf16 (feeds MFMA GEMMs)
// ---------------------------------------------------------------------------
__device__ __forceinline__ void ln_core(const float* __restrict__ xr,
                                        const float* __restrict__ g,
                                        const float* __restrict__ bb,
                                        float* o0, float* o1, int tid)
{
    float v0 = xr[tid], v1 = xr[tid + 256];
    float s = v0 + v1, q2 = v0 * v0 + v1 * v1;
#pragma unroll
    for (int o = 32; o; o >>= 1) { s += __shfl_xor(s, o); q2 += __shfl_xor(q2, o); }
    __shared__ float rs[4], rq[4];
    int lane = tid & 63, wid = tid >> 6;
    if (lane == 0) { rs[wid] = s; rq[wid] = q2; }
    __syncthreads();
    s = rs[0] + rs[1] + rs[2] + rs[3];
    q2 = rq[0] + rq[1] + rq[2] + rq[3];
    float mean = s * (1.f / (float)D);
    float var = q2 * (1.f / (float)D) - mean * mean;
    float rstd = rsqrtf(var + 1e-6f);
    *o0 = (v0 - mean) * rstd * g[tid] + bb[tid];
    *o1 = (v1 - mean) * rstd * g[tid + 256] + bb[tid + 256];
}

__global__ __launch_bounds__(256) void ln_kernel(const float* __restrict__ x,
                                                 unsigned short* __restrict__ y,
                                                 const float* __restrict__ g,
                                                 const float* __restrict__ bb)
{
    int row = blockIdx.x, tid = threadIdx.x;
    float o0, o1;
    ln_core(x + (size_t)row * D, g, bb, &o0, &o1, tid);
    y[(size_t)row * D + tid] = f2bf(o0);
    y[(size_t)row * D + tid + 256] = f2bf(o1);
}

__global__ __launch_bounds__(256) void final_ln_kernel(const float* __restrict__ x,
                                                       float* __restrict__ out,
                                                       const float* __restrict__ g,
                                                       const float* __restrict__ bb)
{
    int row = blockIdx.x, tid = threadIdx.x;   // row = b*T + t
    int b = row >> 8, t = row & (T - 1);
    float o0, o1;
    ln_core(x + (size_t)row * D, g, bb, &o0, &o1, tid);
    float* op = out + ((size_t)t * B + b) * D; // (T,B,D)
    op[tid] = o0;
    op[tid + 256] = o1;
}

// ---------------------------------------------------------------------------
// per-layer weight f32->bf16 conversion (+ QKV concat, rel table bf16 pad-48)
// grid: 1548 blocks x 256 (396288 groups of 8 elems)
// ---------------------------------------------------------------------------
__global__ __launch_bounds__(256) void convert_layer_kernel(
    const float* __restrict__ Wq, const float* __restrict__ Wk, const float* __restrict__ Wv,
    const float* __restrict__ Wo, const float* __restrict__ W1, const float* __restrict__ W2,
    const float* __restrict__ bq, const float* __restrict__ bk, const float* __restrict__ bv,
    const float* __restrict__ rel, int l,
    unsigned short* __restrict__ WQKVb, unsigned short* __restrict__ Wob,
    unsigned short* __restrict__ W1b, unsigned short* __restrict__ W2b,
    unsigned short* __restrict__ relb,
    float* __restrict__ bqkv)
{
    int g = blockIdx.x * 256 + threadIdx.x;   // 0 .. 396287
    const float* src; unsigned short* dst;
    bool zero = false;
    if (g < 98304) {
        int e = g * 8; int piece = e >> 18; int rem = e & 262143;
        src = (piece == 0 ? Wq : piece == 1 ? Wk : Wv) + (size_t)l * 262144 + rem;
        dst = WQKVb + e;
    } else if (g < 131072) {
        int e = (g - 98304) * 8;
        src = Wo + (size_t)l * 262144 + e; dst = Wob + e;
    } else if (g < 262144) {
        int e = (g - 131072) * 8;
        src = W1 + (size_t)l * 1048576 + e; dst = W1b + e;
    } else if (g < 393216) {
        int e = (g - 262144) * 8;
        src = W2 + (size_t)l * 1048576 + e; dst = W2b + e;
    } else {
        int e = (g - 393216) * 8;             // 48 x 512 rel table
        int row = e >> 9, cc = e & 511;
        dst = relb + e;
        if (row < BUCKETS + 1) src = rel + ((size_t)l * (BUCKETS + 1) + row) * 512 + cc;
        else { src = nullptr; zero = true; }
    }
    uint4 o;
    if (zero) { o.x = o.y = o.z = o.w = 0u; }
    else {
        float4 x = *(const float4*)src, y = *(const float4*)(src + 4);
        o.x = (unsigned)f2bf(x.x) | ((unsigned)f2bf(x.y) << 16);
        o.y = (unsigned)f2bf(x.z) | ((unsigned)f2bf(x.w) << 16);
        o.z = (unsigned)f2bf(y.x) | ((unsigned)f2bf(y.y) << 16);
        o.w = (unsigned)f2bf(y.z) | ((unsigned)f2bf(y.w) << 16);
    }
    *(uint4*)dst = o;
    if (g < 3 * D) {
        int piece = g >> 9, r2 = g & 511;
        bqkv[g] = (piece == 0 ? bq : piece == 1 ? bk : bv)[l * 512 + r2];
    }
}

// ---------------------------------------------------------------------------
// bf16 MFMA GEMM (m97 structure): 128x128 tile, BK=32, 4 waves, XOR-swizzled
// ---------------------------------------------------------------------------
template <bool RELU, bool RESID, bool OUTBF16>
__global__ __launch_bounds__(256) void mgemm_kernel(
    const unsigned short* __restrict__ A,
    const unsigned short* __restrict__ W,
    const float* __restrict__ bias,
    const float* __restrict__ resid,
    void* __restrict__ Cv,
    int N, int M, int K)
{
    __shared__ short smA[2][128 * 32];
    __shared__ short smB[2][128 * 32];
    int tid = threadIdx.x;
    int bn = blockIdx.y * 128;   // output rows
    int bm = blockIdx.x * 128;   // output cols
    const unsigned short* Ab = A + (size_t)bn * K;
    const unsigned short* Wb = W + (size_t)bm * K;

    f32x4 acc[4][4];
#pragma unroll
    for (int i = 0; i < 4; i++)
#pragma unroll
        for (int j = 0; j < 4; j++) acc[i][j] = (f32x4){0.f, 0.f, 0.f, 0.f};

    const int c0 = tid, c1 = tid + 256;
    const int r0 = c0 >> 2, p0 = c0 & 3, l0 = p0 ^ ((r0 >> 1) & 3);
    const int r1 = c1 >> 2, p1 = c1 & 3, l1 = p1 ^ ((r1 >> 1) & 3);

    auto stage = [&](int buf, int k0) {
        stage16(Ab + (size_t)r0 * K + k0 + l0 * 8, &smA[buf][c0 * 8]);
        stage16(Ab + (size_t)r1 * K + k0 + l1 * 8, &smA[buf][c1 * 8]);
        stage16(Wb + (size_t)r0 * K + k0 + l0 * 8, &smB[buf][c0 * 8]);
        stage16(Wb + (size_t)r1 * K + k0 + l1 * 8, &smB[buf][c1 * 8]);
    };

    const int lane = tid & 63;
    const int wv = tid >> 6, wr = wv >> 1, wc = wv & 1;
    int aoff[4], boff[4];
#pragma unroll
    for (int i = 0; i < 4; i++) {
        int ra = wr * 64 + i * 16 + (lane & 15);
        int ca = (lane >> 4) ^ ((ra >> 1) & 3);
        aoff[i] = ra * 32 + ca * 8;
        int rb = wc * 64 + i * 16 + (lane & 15);
        int cb = (lane >> 4) ^ ((rb >> 1) & 3);
        boff[i] = rb * 32 + cb * 8;
    }

    stage(0, 0);
    const int nkt = K >> 5;
    for (int kt = 0; kt < nkt; ++kt) {
        __syncthreads();
        int cur = kt & 1;
        if (kt + 1 < nkt) stage(cur ^ 1, (kt + 1) << 5);
        const short* sa = smA[cur];
        const short* sb = smB[cur];
        bf16x8 af[4], bfr[4];
#pragma unroll
        for (int i = 0; i < 4; i++) af[i] = *(const bf16x8*)(sa + aoff[i]);
#pragma unroll
        for (int j = 0; j < 4; j++) bfr[j] = *(const bf16x8*)(sb + boff[j]);
#pragma unroll
        for (int i = 0; i < 4; i++)
#pragma unroll
            for (int j = 0; j < 4; j++)
                acc[i][j] = __builtin_amdgcn_mfma_f32_16x16x32_bf16(af[i], bfr[j], acc[i][j], 0, 0, 0);
    }

#pragma unroll
    for (int j = 0; j < 4; j++) {
        int col = bm + wc * 64 + j * 16 + (lane & 15);
        float bval = bias[col];
#pragma unroll
        for (int i = 0; i < 4; i++) {
            f32x4 v = acc[i][j];
#pragma unroll
            for (int r = 0; r < 4; r++) {
                int row = bn + wr * 64 + i * 16 + (lane >> 4) * 4 + r;
                float val = v[r] + bval;
                if (RELU) val = fmaxf(val, 0.f);
                if (RESID) val += resid[(size_t)row * M + col];
                if (OUTBF16) ((unsigned short*)Cv)[(size_t)row * M + col] = f2bf(val);
                else         ((float*)Cv)[(size_t)row * M + col] = val;
            }
        }
    }
}

// ---------------------------------------------------------------------------
// prep: per (b,h) block: uk[bh][ki] = u_h . k_row ;  VT[bh][d][ki] = V[ki][d]
// qkv is bf16 [2048][1536] (q|k|v)
// ---------------------------------------------------------------------------
__global__ __launch_bounds__(256) void prep_kernel(const unsigned short* __restrict__ qkv,
                                                   const float* __restrict__ u,
                                                   float* __restrict__ uk,
                                                   unsigned short* __restrict__ vt)
{
    int bh = blockIdx.x, b = bh >> 3, h = bh & 7;
    int tid = threadIdx.x, w = tid >> 6, lane = tid & 63;
    __shared__ unsigned short Vs[256][66];
    float uh = u[h * 64 + lane];
    for (int row = w * 64; row < w * 64 + 64; row++) {
        const unsigned short* rp = qkv + (size_t)(b * T + row) * QKVLD + h * 64;
        float kv = bf2f(rp[512 + lane]);
        float s = uh * kv;
#pragma unroll
        for (int o = 32; o; o >>= 1) s += __shfl_xor(s, o);
        if (lane == 0) uk[bh * 256 + row] = s;
        Vs[row][lane] = rp[1024 + lane];
    }
    __syncthreads();
    int d = tid >> 2, kc = (tid & 3) * 64;
    unsigned short* op = vt + (size_t)(bh * 64 + d) * 256 + kc;
#pragma unroll
    for (int u4 = 0; u4 < 8; u4++) {
        uint4 o;
        unsigned int xw[4];
#pragma unroll
        for (int q = 0; q < 4; q++) {
            int i = u4 * 8 + q * 2;
            xw[q] = (unsigned int)Vs[kc + i][d] | ((unsigned int)Vs[kc + i + 1][d] << 16);
        }
        o.x = xw[0]; o.y = xw[1]; o.z = xw[2]; o.w = xw[3];
        *(uint4*)(op + u4 * 8) = o;
    }
}

// ---------------------------------------------------------------------------
// Fused MFMA attention: grid (B*H, T/64), 256 thr = 4 independent waves.
// Each wave: 16 q-rows. S = 0.125*(Q K^T) + uk + qrel[dist]; softmax (wave-
// local shuffles); P (bf16, swizzled LDS) @ V^T (global) -> ctx bf16.
// qrel computed in-kernel via MFMA vs relb (48x512 bf16, rows>=33 zero).
// ---------------------------------------------------------------------------
__global__ __launch_bounds__(256) void fattn_kernel(
    const unsigned short* __restrict__ qkv,
    const unsigned short* __restrict__ vt,
    const float* __restrict__ uk,
    const unsigned short* __restrict__ relb,
    const float* __restrict__ vvec,
    const int* __restrict__ dist,
    const int* __restrict__ lengths,
    unsigned short* __restrict__ ctx)
{
    __shared__ unsigned short Ps[4][16][256];
    __shared__ float Qrel[4][16][49];

    int bh = blockIdx.x, b = bh >> 3, h = bh & 7;
    int qi0 = blockIdx.y * 64;
    int tid = threadIdx.x, w = tid >> 6, lane = tid & 63;
    int l15 = lane & 15, g = lane >> 4;
    int qr = qi0 + w * 16;                       // global row of strip base

    // ---- Q fragments (raw q, unscaled) ----
    const unsigned short* qbase = qkv + (size_t)(b * T + qr + l15) * QKVLD + h * 64 + g * 8;
    bf16x8 qa0 = *(const bf16x8*)(qbase);
    bf16x8 qa1 = *(const bf16x8*)(qbase + 32);

    // ---- qrel = (0.125*q + v) . rel  via MFMA ----
    {
        const float* vp = vvec + h * 64 + g * 8;
        float va0[8], va1[8];
        *(float4*)&va0[0] = *(const float4*)(vp);
        *(float4*)&va0[4] = *(const float4*)(vp + 4);
        *(float4*)&va1[0] = *(const float4*)(vp + 32);
        *(float4*)&va1[4] = *(const float4*)(vp + 36);
        bf16x8 qh0, qh1;
#pragma unroll
        for (int e = 0; e < 8; e++) {
            qh0[e] = (short)f2bf(0.125f * bf2f((unsigned short)qa0[e]) + va0[e]);
            qh1[e] = (short)f2bf(0.125f * bf2f((unsigned short)qa1[e]) + va1[e]);
        }
        f32x4 qacc[3];
#pragma unroll
        for (int j = 0; j < 3; j++) qacc[j] = (f32x4){0.f, 0.f, 0.f, 0.f};
#pragma unroll
        for (int j = 0; j < 3; j++) {
            const unsigned short* rp = relb + (size_t)(j * 16 + l15) * 512 + h * 64 + g * 8;
            bf16x8 r0 = *(const bf16x8*)(rp);
            bf16x8 r1 = *(const bf16x8*)(rp + 32);
            qacc[j] = __builtin_amdgcn_mfma_f32_16x16x32_bf16(qh0, r0, qacc[j], 0, 0, 0);
            qacc[j] = __builtin_amdgcn_mfma_f32_16x16x32_bf16(qh1, r1, qacc[j], 0, 0, 0);
        }
#pragma unroll
        for (int j = 0; j < 3; j++)
#pragma unroll
            for (int r = 0; r < 4; r++)
                Qrel[w][g * 4 + r][j * 16 + l15] = qacc[j][r];
    }

    // ---- S = Q K^T (raw) ----
    f32x4 acc[16];
#pragma unroll
    for (int j = 0; j < 16; j++) acc[j] = (f32x4){0.f, 0.f, 0.f, 0.f};
    const unsigned short* kbase = qkv + (size_t)(b * T) * QKVLD + 512 + h * 64 + g * 8;
#pragma unroll
    for (int j = 0; j < 16; j++) {
        const unsigned short* kp = kbase + (size_t)(j * 16 + l15) * QKVLD;
        bf16x8 k0 = *(const bf16x8*)(kp);
        bf16x8 k1 = *(const bf16x8*)(kp + 32);
        acc[j] = __builtin_amdgcn_mfma_f32_16x16x32_bf16(qa0, k0, acc[j], 0, 0, 0);
        acc[j] = __builtin_amdgcn_mfma_f32_16x16x32_bf16(qa1, k1, acc[j], 0, 0, 0);
    }

    float ukf[16];
#pragma unroll
    for (int j = 0; j < 16; j++) ukf[j] = uk[bh * 256 + j * 16 + l15];

    // ---- softmax (wave-local) + P -> bf16 swizzled LDS ----
    int len = lengths[b];
    float rinv[4];
    const int* db = dist + (size_t)b * T * T;
#pragma unroll
    for (int r = 0; r < 4; r++) {
        int rowloc = g * 4 + r;
        int qrow = qr + rowloc;
        const int* dpr = db + (size_t)qrow * T;
        float m = -3.0e38f;
#pragma unroll
        for (int j = 0; j < 16; j++) {
            int ki = j * 16 + l15;
            int dv = dpr[ki];
            float s = 0.125f * acc[j][r] + ukf[j] + Qrel[w][rowloc][dv];
            s = (ki < len) ? s : -1.0e30f;
            acc[j][r] = s;
            m = fmaxf(m, s);
        }
#pragma unroll
        for (int o = 8; o; o >>= 1) m = fmaxf(m, __shfl_xor(m, o));
        float sum = 0.f;
#pragma unroll
        for (int j = 0; j < 16; j++) {
            int ki = j * 16 + l15;
            float p = __expf(acc[j][r] - m);
            sum += p;
            int cph = ((ki >> 3) ^ (rowloc & 7));
            Ps[w][rowloc][cph * 8 + (ki & 7)] = f2bf(p);
        }
#pragma unroll
        for (int o = 8; o; o >>= 1) sum += __shfl_xor(sum, o);
        rinv[r] = 1.0f / sum;
    }

    // ---- O = P V  (A from LDS strip, B from global VT) ----
    f32x4 oacc[4];
#pragma unroll
    for (int j = 0; j < 4; j++) oacc[j] = (f32x4){0.f, 0.f, 0.f, 0.f};
    const unsigned short* vtb = vt + (size_t)bh * 64 * 256;
#pragma unroll
    for (int ks = 0; ks < 8; ks++) {
        int c = ks * 4 + g;
        int cph = c ^ (l15 & 7);
        bf16x8 pa = *(const bf16x8*)&Ps[w][l15][cph * 8];
#pragma unroll
        for (int j2 = 0; j2 < 4; j2++) {
            bf16x8 vb = *(const bf16x8*)(vtb + (size_t)(j2 * 16 + l15) * 256 + c * 8);
            oacc[j2] = __builtin_amdgcn_mfma_f32_16x16x32_bf16(pa, vb, oacc[j2], 0, 0, 0);
        }
    }

    // ---- write ctx bf16 ----
#pragma unroll
    for (int j2 = 0; j2 < 4; j2++) {
#pragma unroll
        for (int r = 0; r < 4; r++) {
            int qrow = qr + g * 4 + r;
            int dcol = j2 * 16 + l15;
            ctx[(size_t)(b * T + qrow) * D + h * 64 + dcol] = f2bf(oacc[j2][r] * rinv[r]);
        }
    }
}

// ---------------------------------------------------------------------------
extern "C" void kernel_launch(void* const* d_in, const int* in_sizes, int n_in,
                              void* d_out, int out_size, void* d_ws, size_t ws_size,
                              hipStream_t stream)
{
    const float* src     = (const float*)d_in[0];
    const int*   lengths = (const int*)d_in[1];
    const int*   dist    = (const int*)d_in[2];
    const float* u       = (const float*)d_in[3];
    const float* v       = (const float*)d_in[4];
    const float* ln1_g   = (const float*)d_in[5];
    const float* ln1_b   = (const float*)d_in[6];
    const float* Wq      = (const float*)d_in[7];
    const float* Wk      = (const float*)d_in[8];
    const float* Wv      = (const float*)d_in[9];
    const float* Wo      = (const float*)d_in[10];
    const float* bq      = (const float*)d_in[11];
    const float* bk      = (const float*)d_in[12];
    const float* bv      = (const float*)d_in[13];
    const float* bo      = (const float*)d_in[14];
    const float* rel     = (const float*)d_in[15];
    const float* fg      = (const float*)d_in[16];
    const float* fb      = (const float*)d_in[17];
    const float* W1      = (const float*)d_in[18];
    const float* b1      = (const float*)d_in[19];
    const float* W2      = (const float*)d_in[20];
    const float* b2      = (const float*)d_in[21];
    const float* flg     = (const float*)d_in[22];
    const float* flb     = (const float*)d_in[23];

    float* ws = (float*)d_ws;
    float*          X     = ws;                                   // 1048576 f
    unsigned short* QKVb  = (unsigned short*)(ws + 1048576);      // 3145728 bf16
    unsigned short* Hb    = (unsigned short*)(ws + 2621440);      // 1048576 bf16
    unsigned short* CTX   = (unsigned short*)(ws + 3145728);      // 1048576 bf16
    unsigned short* FF1   = (unsigned short*)(ws + 3670016);      // 4194304 bf16
    unsigned short* VT    = (unsigned short*)(ws + 5767168);      // 1048576 bf16
    float*          UK    = ws + 6291456;                         // 16384 f
    unsigned short* WQKVb = (unsigned short*)(ws + 6307840);      // 786432 bf16
    unsigned short* Wob   = (unsigned short*)(ws + 6701056);      // 262144 bf16
    unsigned short* W1b   = (unsigned short*)(ws + 6832128);      // 1048576 bf16
    unsigned short* W2b   = (unsigned short*)(ws + 7356416);      // 1048576 bf16
    float*          bqkv  = ws + 7880704;                         // 1536 f
    unsigned short* RELb  = (unsigned short*)(ws + 7882240);      // 24576 bf16

    embed_kernel<<<4096, 256, 0, stream>>>(src, X);

    for (int l = 0; l < L; l++) {
        convert_layer_kernel<<<1548, 256, 0, stream>>>(
            Wq, Wk, Wv, Wo, W1, W2, bq, bk, bv, rel, l,
            WQKVb, Wob, W1b, W2b, RELb, bqkv);

        ln_kernel<<<NT, 256, 0, stream>>>(X, Hb, ln1_g + l * D, ln1_b + l * D);

        // fused QKV: (2048 x 1536) bf16 out
        mgemm_kernel<false, false, true><<<dim3(12, 16), 256, 0, stream>>>(
            Hb, WQKVb, bqkv, nullptr, QKVb, NT, QKVLD, D);

        prep_kernel<<<64, 256, 0, stream>>>(QKVb, u, UK, VT);

        fattn_kernel<<<dim3(B * H, T / 64), 256, 0, stream>>>(
            QKVb, VT, UK, RELb, v, dist, lengths, CTX);

        mgemm_kernel<false, true, false><<<dim3(4, 16), 256, 0, stream>>>(
            CTX, Wob, bo + l * D, X, X, NT, D, D);

        ln_kernel<<<NT, 256, 0, stream>>>(X, Hb, fg + l * D, fb + l * D);

        mgemm_kernel<true, false, true><<<dim3(16, 16), 256, 0, stream>>>(
            Hb, W1b, b1 + l * DFF, nullptr, FF1, NT, DFF, D);

        mgemm_kernel<false, true, false><<<dim3(4, 16), 256, 0, stream>>>(
            FF1, W2b, b2 + l * D, X, X, NT, D, DFF);
    }

    final_ln_kernel<<<NT, 256, 0, stream>>>(X, (float*)d_out, flg, flb);
}

// Round 4
// 617.069 us; speedup vs baseline: 2.7538x; 1.2846x over previous
//
#include <hip/hip_runtime.h>
#include <hip/hip_bf16.h>
#include <math.h>

constexpr int L = 4, D = 512, H = 8, DFF = 2048, T = 256, B = 8, BUCKETS = 32;
constexpr int DH = D / H;          // 64
constexpr int NT = B * T;          // 2048 rows
constexpr int QKVLD = 3 * D;       // 1536

typedef __attribute__((ext_vector_type(8))) short bf16x8;
typedef __attribute__((ext_vector_type(4))) float f32x4;

__device__ __forceinline__ unsigned short f2bf(float f) {
    unsigned int x = __float_as_uint(f);
    return (unsigned short)((x + 0x7fffu + ((x >> 16) & 1u)) >> 16);
}
__device__ __forceinline__ float bf2f(unsigned short u) {
    return __uint_as_float((unsigned int)u << 16);
}

__device__ __forceinline__ void stage16(const unsigned short* g, short* l) {
    __builtin_amdgcn_global_load_lds((const __attribute__((address_space(1))) unsigned int*)g,
                                     (__attribute__((address_space(3))) unsigned int*)l,
                                     16, 0, 0);
}

// ---------------------------------------------------------------------------
// embed: x[b,t,d] = src[t,b,d]*sqrt(D) + pe[t,d]
// ---------------------------------------------------------------------------
__global__ __launch_bounds__(256) void embed_kernel(const float* __restrict__ src,
                                                    float* __restrict__ x)
{
    int idx = blockIdx.x * 256 + threadIdx.x;        // over B*T*D = 1M
    int d = idx & (D - 1);
    int t = (idx >> 9) & (T - 1);
    int b = idx >> 17;
    int i = d >> 1;
    float div = expf(-(float)(2 * i) * (9.210340371976184f / (float)D)); // ln(10000)
    float ang = (float)t * div;
    float pe = (d & 1) ? cosf(ang) : sinf(ang);
    x[idx] = src[((size_t)t * B + b) * D + d] * 22.62741699796952f + pe; // sqrt(512)
}

// ---------------------------------------------------------------------------
// LayerNorm over D=512; writes bf16 (feeds MFMA GEMMs)
// ---------------------------------------------------------------------------
__device__ __forceinline__ void ln_core(const float* __restrict__ xr,
                                        const float* __restrict__ g,
                                        const float* __restrict__ bb,
                                        float* o0, float* o1, int tid)
{
    float v0 = xr[tid], v1 = xr[tid + 256];
    float s = v0 + v1, q2 = v0 * v0 + v1 * v1;
#pragma unroll
    for (int o = 32; o; o >>= 1) { s += __shfl_xor(s, o); q2 += __shfl_xor(q2, o); }
    __shared__ float rs[4], rq[4];
    int lane = tid & 63, wid = tid >> 6;
    if (lane == 0) { rs[wid] = s; rq[wid] = q2; }
    __syncthreads();
    s = rs[0] + rs[1] + rs[2] + rs[3];
    q2 = rq[0] + rq[1] + rq[2] + rq[3];
    float mean = s * (1.f / (float)D);
    float var = q2 * (1.f / (float)D) - mean * mean;
    float rstd = rsqrtf(var + 1e-6f);
    *o0 = (v0 - mean) * rstd * g[tid] + bb[tid];
    *o1 = (v1 - mean) * rstd * g[tid + 256] + bb[tid + 256];
}

__global__ __launch_bounds__(256) void ln_kernel(const float* __restrict__ x,
                                                 unsigned short* __restrict__ y,
                                                 const float* __restrict__ g,
                                                 const float* __restrict__ bb)
{
    int row = blockIdx.x, tid = threadIdx.x;
    float o0, o1;
    ln_core(x + (size_t)row * D, g, bb, &o0, &o1, tid);
    y[(size_t)row * D + tid] = f2bf(o0);
    y[(size_t)row * D + tid + 256] = f2bf(o1);
}

__global__ __launch_bounds__(256) void final_ln_kernel(const float* __restrict__ x,
                                                       float* __restrict__ out,
                                                       const float* __restrict__ g,
                                                       const float* __restrict__ bb)
{
    int row = blockIdx.x, tid = threadIdx.x;   // row = b*T + t
    int b = row >> 8, t = row & (T - 1);
    float o0, o1;
    ln_core(x + (size_t)row * D, g, bb, &o0, &o1, tid);
    float* op = out + ((size_t)t * B + b) * D; // (T,B,D)
    op[tid] = o0;
    op[tid + 256] = o1;
}

// ---------------------------------------------------------------------------
// per-layer weight f32->bf16 conversion (+ QKV concat, rel table bf16 pad-48)
// grid: 1548 blocks x 256 (396288 groups of 8 elems)
// ---------------------------------------------------------------------------
__global__ __launch_bounds__(256) void convert_layer_kernel(
    const float* __restrict__ Wq, const float* __restrict__ Wk, const float* __restrict__ Wv,
    const float* __restrict__ Wo, const float* __restrict__ W1, const float* __restrict__ W2,
    const float* __restrict__ bq, const float* __restrict__ bk, const float* __restrict__ bv,
    const float* __restrict__ rel, int l,
    unsigned short* __restrict__ WQKVb, unsigned short* __restrict__ Wob,
    unsigned short* __restrict__ W1b, unsigned short* __restrict__ W2b,
    unsigned short* __restrict__ relb,
    float* __restrict__ bqkv)
{
    int g = blockIdx.x * 256 + threadIdx.x;   // 0 .. 396287
    const float* src; unsigned short* dst;
    bool zero = false;
    if (g < 98304) {
        int e = g * 8; int piece = e >> 18; int rem = e & 262143;
        src = (piece == 0 ? Wq : piece == 1 ? Wk : Wv) + (size_t)l * 262144 + rem;
        dst = WQKVb + e;
    } else if (g < 131072) {
        int e = (g - 98304) * 8;
        src = Wo + (size_t)l * 262144 + e; dst = Wob + e;
    } else if (g < 262144) {
        int e = (g - 131072) * 8;
        src = W1 + (size_t)l * 1048576 + e; dst = W1b + e;
    } else if (g < 393216) {
        int e = (g - 262144) * 8;
        src = W2 + (size_t)l * 1048576 + e; dst = W2b + e;
    } else {
        int e = (g - 393216) * 8;             // 48 x 512 rel table
        int row = e >> 9, cc = e & 511;
        dst = relb + e;
        if (row < BUCKETS + 1) src = rel + ((size_t)l * (BUCKETS + 1) + row) * 512 + cc;
        else { src = nullptr; zero = true; }
    }
    uint4 o;
    if (zero) { o.x = o.y = o.z = o.w = 0u; }
    else {
        float4 x = *(const float4*)src, y = *(const float4*)(src + 4);
        o.x = (unsigned)f2bf(x.x) | ((unsigned)f2bf(x.y) << 16);
        o.y = (unsigned)f2bf(x.z) | ((unsigned)f2bf(x.w) << 16);
        o.z = (unsigned)f2bf(y.x) | ((unsigned)f2bf(y.y) << 16);
        o.w = (unsigned)f2bf(y.z) | ((unsigned)f2bf(y.w) << 16);
    }
    *(uint4*)dst = o;
    if (g < 3 * D) {
        int piece = g >> 9, r2 = g & 511;
        bqkv[g] = (piece == 0 ? bq : piece == 1 ? bk : bv)[l * 512 + r2];
    }
}

// ---------------------------------------------------------------------------
// bf16 MFMA GEMM (m97 structure): 128x128 tile, BK=32, 4 waves, XOR-swizzled
// ---------------------------------------------------------------------------
template <bool RELU, bool RESID, bool OUTBF16>
__global__ __launch_bounds__(256) void mgemm_kernel(
    const unsigned short* __restrict__ A,
    const unsigned short* __restrict__ W,
    const float* __restrict__ bias,
    const float* __restrict__ resid,
    void* __restrict__ Cv,
    int N, int M, int K)
{
    __shared__ short smA[2][128 * 32];
    __shared__ short smB[2][128 * 32];
    int tid = threadIdx.x;
    int bn = blockIdx.y * 128;   // output rows
    int bm = blockIdx.x * 128;   // output cols
    const unsigned short* Ab = A + (size_t)bn * K;
    const unsigned short* Wb = W + (size_t)bm * K;

    f32x4 acc[4][4];
#pragma unroll
    for (int i = 0; i < 4; i++)
#pragma unroll
        for (int j = 0; j < 4; j++) acc[i][j] = (f32x4){0.f, 0.f, 0.f, 0.f};

    const int c0 = tid, c1 = tid + 256;
    const int r0 = c0 >> 2, p0 = c0 & 3, l0 = p0 ^ ((r0 >> 1) & 3);
    const int r1 = c1 >> 2, p1 = c1 & 3, l1 = p1 ^ ((r1 >> 1) & 3);

    auto stage = [&](int buf, int k0) {
        stage16(Ab + (size_t)r0 * K + k0 + l0 * 8, &smA[buf][c0 * 8]);
        stage16(Ab + (size_t)r1 * K + k0 + l1 * 8, &smA[buf][c1 * 8]);
        stage16(Wb + (size_t)r0 * K + k0 + l0 * 8, &smB[buf][c0 * 8]);
        stage16(Wb + (size_t)r1 * K + k0 + l1 * 8, &smB[buf][c1 * 8]);
    };

    const int lane = tid & 63;
    const int wv = tid >> 6, wr = wv >> 1, wc = wv & 1;
    int aoff[4], boff[4];
#pragma unroll
    for (int i = 0; i < 4; i++) {
        int ra = wr * 64 + i * 16 + (lane & 15);
        int ca = (lane >> 4) ^ ((ra >> 1) & 3);
        aoff[i] = ra * 32 + ca * 8;
        int rb = wc * 64 + i * 16 + (lane & 15);
        int cb = (lane >> 4) ^ ((rb >> 1) & 3);
        boff[i] = rb * 32 + cb * 8;
    }

    stage(0, 0);
    const int nkt = K >> 5;
    for (int kt = 0; kt < nkt; ++kt) {
        __syncthreads();
        int cur = kt & 1;
        if (kt + 1 < nkt) stage(cur ^ 1, (kt + 1) << 5);
        const short* sa = smA[cur];
        const short* sb = smB[cur];
        bf16x8 af[4], bfr[4];
#pragma unroll
        for (int i = 0; i < 4; i++) af[i] = *(const bf16x8*)(sa + aoff[i]);
#pragma unroll
        for (int j = 0; j < 4; j++) bfr[j] = *(const bf16x8*)(sb + boff[j]);
#pragma unroll
        for (int i = 0; i < 4; i++)
#pragma unroll
            for (int j = 0; j < 4; j++)
                acc[i][j] = __builtin_amdgcn_mfma_f32_16x16x32_bf16(af[i], bfr[j], acc[i][j], 0, 0, 0);
    }

#pragma unroll
    for (int j = 0; j < 4; j++) {
        int col = bm + wc * 64 + j * 16 + (lane & 15);
        float bval = bias[col];
#pragma unroll
        for (int i = 0; i < 4; i++) {
            f32x4 v = acc[i][j];
#pragma unroll
            for (int r = 0; r < 4; r++) {
                int row = bn + wr * 64 + i * 16 + (lane >> 4) * 4 + r;
                float val = v[r] + bval;
                if (RELU) val = fmaxf(val, 0.f);
                if (RESID) val += resid[(size_t)row * M + col];
                if (OUTBF16) ((unsigned short*)Cv)[(size_t)row * M + col] = f2bf(val);
                else         ((float*)Cv)[(size_t)row * M + col] = val;
            }
        }
    }
}

// ---------------------------------------------------------------------------
// V transpose: VT[bh][d][ki] = V[b,ki,h*64+d]. grid (64 bh, 4 k-chunks).
// 64x64 bf16 tile through LDS (rows padded to 66 shorts).
// ---------------------------------------------------------------------------
__global__ __launch_bounds__(256) void vtrans_kernel(const unsigned short* __restrict__ qkv,
                                                     unsigned short* __restrict__ vt)
{
    __shared__ unsigned short tile[64 * 66];
    int bh = blockIdx.x, b = bh >> 3, h = bh & 7;
    int kc = blockIdx.y * 64;
    int tid = threadIdx.x;
    int r = tid >> 2, c0 = (tid & 3) * 16;
    const unsigned short* rp = qkv + (size_t)(b * T + kc + r) * QKVLD + 2 * D + h * 64 + c0;
    uint4 w0 = *(const uint4*)rp;
    uint4 w1 = *(const uint4*)(rp + 8);
    unsigned short* tp = &tile[r * 66 + c0];
    unsigned int ww[8] = {w0.x, w0.y, w0.z, w0.w, w1.x, w1.y, w1.z, w1.w};
#pragma unroll
    for (int e = 0; e < 8; e++) {
        tp[2 * e]     = (unsigned short)(ww[e] & 0xffffu);
        tp[2 * e + 1] = (unsigned short)(ww[e] >> 16);
    }
    __syncthreads();
    int d = tid >> 2, k0 = (tid & 3) * 16;
    unsigned int outw[8];
#pragma unroll
    for (int i = 0; i < 8; i++) {
        unsigned int lo = tile[(k0 + 2 * i) * 66 + d];
        unsigned int hi = tile[(k0 + 2 * i + 1) * 66 + d];
        outw[i] = lo | (hi << 16);
    }
    unsigned short* op = vt + (size_t)(bh * 64 + d) * 256 + kc + k0;
    *(uint4*)op = *(uint4*)&outw[0];
    *(uint4*)(op + 8) = *(uint4*)&outw[4];
}

// ---------------------------------------------------------------------------
// Fused MFMA attention: grid (B*H, T/64), 256 thr = 4 independent waves.
// Each wave: 16 q-rows. S = (0.125q+u) K^T + qrel[dist]; softmax (wave-local
// shuffles); P (bf16, swizzled LDS) @ V^T (global) -> ctx bf16.
// qrel computed in-kernel via MFMA vs relb (48x512 bf16, rows>=33 zero).
// ---------------------------------------------------------------------------
__global__ __launch_bounds__(256) void fattn_kernel(
    const unsigned short* __restrict__ qkv,
    const unsigned short* __restrict__ vt,
    const unsigned short* __restrict__ relb,
    const float* __restrict__ uvec,
    const float* __restrict__ vvec,
    const int* __restrict__ dist,
    const int* __restrict__ lengths,
    unsigned short* __restrict__ ctx)
{
    __shared__ unsigned short Ps[4][16][256];
    __shared__ float Qrel[4][16][49];

    int bh = blockIdx.x, b = bh >> 3, h = bh & 7;
    int qi0 = blockIdx.y * 64;
    int tid = threadIdx.x, w = tid >> 6, lane = tid & 63;
    int l15 = lane & 15, g = lane >> 4;
    int qr = qi0 + w * 16;                       // global row of strip base

    // ---- Q fragments (raw q) + (0.125q+u) and (0.125q+v) variants ----
    const unsigned short* qbase = qkv + (size_t)(b * T + qr + l15) * QKVLD + h * 64 + g * 8;
    bf16x8 qa0 = *(const bf16x8*)(qbase);
    bf16x8 qa1 = *(const bf16x8*)(qbase + 32);

    bf16x8 qu0, qu1;
    {
        const float* up = uvec + h * 64 + g * 8;
        float ua0[8], ua1[8];
        *(float4*)&ua0[0] = *(const float4*)(up);
        *(float4*)&ua0[4] = *(const float4*)(up + 4);
        *(float4*)&ua1[0] = *(const float4*)(up + 32);
        *(float4*)&ua1[4] = *(const float4*)(up + 36);
#pragma unroll
        for (int e = 0; e < 8; e++) {
            qu0[e] = (short)f2bf(0.125f * bf2f((unsigned short)qa0[e]) + ua0[e]);
            qu1[e] = (short)f2bf(0.125f * bf2f((unsigned short)qa1[e]) + ua1[e]);
        }
    }

    // ---- qrel = (0.125*q + v) . rel  via MFMA ----
    {
        const float* vp = vvec + h * 64 + g * 8;
        float va0[8], va1[8];
        *(float4*)&va0[0] = *(const float4*)(vp);
        *(float4*)&va0[4] = *(const float4*)(vp + 4);
        *(float4*)&va1[0] = *(const float4*)(vp + 32);
        *(float4*)&va1[4] = *(const float4*)(vp + 36);
        bf16x8 qh0, qh1;
#pragma unroll
        for (int e = 0; e < 8; e++) {
            qh0[e] = (short)f2bf(0.125f * bf2f((unsigned short)qa0[e]) + va0[e]);
            qh1[e] = (short)f2bf(0.125f * bf2f((unsigned short)qa1[e]) + va1[e]);
        }
        f32x4 qacc[3];
#pragma unroll
        for (int j = 0; j < 3; j++) qacc[j] = (f32x4){0.f, 0.f, 0.f, 0.f};
#pragma unroll
        for (int j = 0; j < 3; j++) {
            const unsigned short* rp = relb + (size_t)(j * 16 + l15) * 512 + h * 64 + g * 8;
            bf16x8 r0 = *(const bf16x8*)(rp);
            bf16x8 r1 = *(const bf16x8*)(rp + 32);
            qacc[j] = __builtin_amdgcn_mfma_f32_16x16x32_bf16(qh0, r0, qacc[j], 0, 0, 0);
            qacc[j] = __builtin_amdgcn_mfma_f32_16x16x32_bf16(qh1, r1, qacc[j], 0, 0, 0);
        }
#pragma unroll
        for (int j = 0; j < 3; j++)
#pragma unroll
            for (int r = 0; r < 4; r++)
                Qrel[w][g * 4 + r][j * 16 + l15] = qacc[j][r];
    }

    // ---- S = (0.125q+u) K^T ----
    f32x4 acc[16];
#pragma unroll
    for (int j = 0; j < 16; j++) acc[j] = (f32x4){0.f, 0.f, 0.f, 0.f};
    const unsigned short* kbase = qkv + (size_t)(b * T) * QKVLD + 512 + h * 64 + g * 8;
#pragma unroll
    for (int j = 0; j < 16; j++) {
        const unsigned short* kp = kbase + (size_t)(j * 16 + l15) * QKVLD;
        bf16x8 k0 = *(const bf16x8*)(kp);
        bf16x8 k1 = *(const bf16x8*)(kp + 32);
        acc[j] = __builtin_amdgcn_mfma_f32_16x16x32_bf16(qu0, k0, acc[j], 0, 0, 0);
        acc[j] = __builtin_amdgcn_mfma_f32_16x16x32_bf16(qu1, k1, acc[j], 0, 0, 0);
    }

    // ---- softmax (wave-local) + P -> bf16 swizzled LDS ----
    int len = lengths[b];
    float rinv[4];
    const int* db = dist + (size_t)b * T * T;
#pragma unroll
    for (int r = 0; r < 4; r++) {
        int rowloc = g * 4 + r;
        int qrow = qr + rowloc;
        const int* dpr = db + (size_t)qrow * T;
        float m = -3.0e38f;
#pragma unroll
        for (int j = 0; j < 16; j++) {
            int ki = j * 16 + l15;
            int dv = dpr[ki];
            float s = acc[j][r] + Qrel[w][rowloc][dv];
            s = (ki < len) ? s : -1.0e30f;
            acc[j][r] = s;
            m = fmaxf(m, s);
        }
#pragma unroll
        for (int o = 8; o; o >>= 1) m = fmaxf(m, __shfl_xor(m, o));
        float sum = 0.f;
#pragma unroll
        for (int j = 0; j < 16; j++) {
            int ki = j * 16 + l15;
            float p = __expf(acc[j][r] - m);
            sum += p;
            int cph = ((ki >> 3) ^ (rowloc & 7));
            Ps[w][rowloc][cph * 8 + (ki & 7)] = f2bf(p);
        }
#pragma unroll
        for (int o = 8; o; o >>= 1) sum += __shfl_xor(sum, o);
        rinv[r] = 1.0f / sum;
    }

    // ---- O = P V  (A from LDS strip, B from global VT) ----
    f32x4 oacc[4];
#pragma unroll
    for (int j = 0; j < 4; j++) oacc[j] = (f32x4){0.f, 0.f, 0.f, 0.f};
    const unsigned short* vtb = vt + (size_t)bh * 64 * 256;
#pragma unroll
    for (int ks = 0; ks < 8; ks++) {
        int c = ks * 4 + g;
        int cph = c ^ (l15 & 7);
        bf16x8 pa = *(const bf16x8*)&Ps[w][l15][cph * 8];
#pragma unroll
        for (int j2 = 0; j2 < 4; j2++) {
            bf16x8 vb = *(const bf16x8*)(vtb + (size_t)(j2 * 16 + l15) * 256 + c * 8);
            oacc[j2] = __builtin_amdgcn_mfma_f32_16x16x32_bf16(pa, vb, oacc[j2], 0, 0, 0);
        }
    }

    // ---- write ctx bf16 ----
#pragma unroll
    for (int j2 = 0; j2 < 4; j2++) {
#pragma unroll
        for (int r = 0; r < 4; r++) {
            int qrow = qr + g * 4 + r;
            int dcol = j2 * 16 + l15;
            ctx[(size_t)(b * T + qrow) * D + h * 64 + dcol] = f2bf(oacc[j2][r] * rinv[r]);
        }
    }
}

// ---------------------------------------------------------------------------
extern "C" void kernel_launch(void* const* d_in, const int* in_sizes, int n_in,
                              void* d_out, int out_size, void* d_ws, size_t ws_size,
                              hipStream_t stream)
{
    const float* src     = (const float*)d_in[0];
    const int*   lengths = (const int*)d_in[1];
    const int*   dist    = (const int*)d_in[2];
    const float* u       = (const float*)d_in[3];
    const float* v       = (const float*)d_in[4];
    const float* ln1_g   = (const float*)d_in[5];
    const float* ln1_b   = (const float*)d_in[6];
    const float* Wq      = (const float*)d_in[7];
    const float* Wk      = (const float*)d_in[8];
    const float* Wv      = (const float*)d_in[9];
    const float* Wo      = (const float*)d_in[10];
    const float* bq      = (const float*)d_in[11];
    const float* bk      = (const float*)d_in[12];
    const float* bv      = (const float*)d_in[13];
    const float* bo      = (const float*)d_in[14];
    const float* rel     = (const float*)d_in[15];
    const float* fg      = (const float*)d_in[16];
    const float* fb      = (const float*)d_in[17];
    const float* W1      = (const float*)d_in[18];
    const float* b1      = (const float*)d_in[19];
    const float* W2      = (const float*)d_in[20];
    const float* b2      = (const float*)d_in[21];
    const float* flg     = (const float*)d_in[22];
    const float* flb     = (const float*)d_in[23];

    float* ws = (float*)d_ws;
    float*          X     = ws;                                   // 1048576 f
    unsigned short* QKVb  = (unsigned short*)(ws + 1048576);      // 3145728 bf16
    unsigned short* Hb    = (unsigned short*)(ws + 2621440);      // 1048576 bf16
    unsigned short* CTX   = (unsigned short*)(ws + 3145728);      // 1048576 bf16
    unsigned short* FF1   = (unsigned short*)(ws + 3670016);      // 4194304 bf16
    unsigned short* VT    = (unsigned short*)(ws + 5767168);      // 1048576 bf16
    unsigned short* WQKVb = (unsigned short*)(ws + 6307840);      // 786432 bf16
    unsigned short* Wob   = (unsigned short*)(ws + 6701056);      // 262144 bf16
    unsigned short* W1b   = (unsigned short*)(ws + 6832128);      // 1048576 bf16
    unsigned short* W2b   = (unsigned short*)(ws + 7356416);      // 1048576 bf16
    float*          bqkv  = ws + 7880704;                         // 1536 f
    unsigned short* RELb  = (unsigned short*)(ws + 7882240);      // 24576 bf16

    embed_kernel<<<4096, 256, 0, stream>>>(src, X);

    for (int l = 0; l < L; l++) {
        convert_layer_kernel<<<1548, 256, 0, stream>>>(
            Wq, Wk, Wv, Wo, W1, W2, bq, bk, bv, rel, l,
            WQKVb, Wob, W1b, W2b, RELb, bqkv);

        ln_kernel<<<NT, 256, 0, stream>>>(X, Hb, ln1_g + l * D, ln1_b + l * D);

        // fused QKV: (2048 x 1536) bf16 out
        mgemm_kernel<false, false, true><<<dim3(12, 16), 256, 0, stream>>>(
            Hb, WQKVb, bqkv, nullptr, QKVb, NT, QKVLD, D);

        vtrans_kernel<<<dim3(64, 4), 256, 0, stream>>>(QKVb, VT);

        fattn_kernel<<<dim3(B * H, T / 64), 256, 0, stream>>>(
            QKVb, VT, RELb, u, v, dist, lengths, CTX);

        mgemm_kernel<false, true, false><<<dim3(4, 16), 256, 0, stream>>>(
            CTX, Wob, bo + l * D, X, X, NT, D, D);

        ln_kernel<<<NT, 256, 0, stream>>>(X, Hb, fg + l * D, fb + l * D);

        mgemm_kernel<true, false, true><<<dim3(16, 16), 256, 0, stream>>>(
            Hb, W1b, b1 + l * DFF, nullptr, FF1, NT, DFF, D);

        mgemm_kernel<false, true, false><<<dim3(4, 16), 256, 0, stream>>>(
            FF1, W2b, b2 + l * D, X, X, NT, D, DFF);
    }

    final_ln_kernel<<<NT, 256, 0, stream>>>(X, (float*)d_out, flg, flb);
}

// Round 5
// 521.841 us; speedup vs baseline: 3.2563x; 1.1825x over previous
//
#include <hip/hip_runtime.h>
#include <hip/hip_bf16.h>
#include <math.h>

constexpr int L = 4, D = 512, H = 8, DFF = 2048, T = 256, B = 8, BUCKETS = 32;
constexpr int DH = D / H;          // 64
constexpr int NT = B * T;          // 2048 rows
constexpr int QKVLD = 3 * D;       // 1536

typedef __attribute__((ext_vector_type(8))) short bf16x8;
typedef __attribute__((ext_vector_type(4))) float f32x4;

__device__ __forceinline__ unsigned short f2bf(float f) {
    unsigned int x = __float_as_uint(f);
    return (unsigned short)((x + 0x7fffu + ((x >> 16) & 1u)) >> 16);
}
__device__ __forceinline__ float bf2f(unsigned short u) {
    return __uint_as_float((unsigned int)u << 16);
}

__device__ __forceinline__ void stage16(const unsigned short* g, short* l) {
    __builtin_amdgcn_global_load_lds((const __attribute__((address_space(1))) unsigned int*)g,
                                     (__attribute__((address_space(3))) unsigned int*)l,
                                     16, 0, 0);
}

// ---------------------------------------------------------------------------
// embed: x[b,t,d] = src[t,b,d]*sqrt(D) + pe[t,d]; one block per t, pe reused
// across the 8 batches.
// ---------------------------------------------------------------------------
__global__ __launch_bounds__(256) void embed_kernel(const float* __restrict__ src,
                                                    float* __restrict__ x)
{
    int t = blockIdx.x, tid = threadIdx.x;
    float pe0, pe1;
    {
        int d0 = tid, d1 = tid + 256;
        float dv0 = expf(-(float)(2 * (d0 >> 1)) * (9.210340371976184f / (float)D));
        float dv1 = expf(-(float)(2 * (d1 >> 1)) * (9.210340371976184f / (float)D));
        float a0 = (float)t * dv0, a1 = (float)t * dv1;
        pe0 = (d0 & 1) ? cosf(a0) : sinf(a0);
        pe1 = (d1 & 1) ? cosf(a1) : sinf(a1);
    }
#pragma unroll
    for (int b = 0; b < B; b++) {
        const float* sp = src + ((size_t)t * B + b) * D;
        float* xp = x + ((size_t)(b * T + t)) * D;
        xp[tid]       = sp[tid]       * 22.62741699796952f + pe0;
        xp[tid + 256] = sp[tid + 256] * 22.62741699796952f + pe1;
    }
}

// ---------------------------------------------------------------------------
// LayerNorm core on two per-thread values (block = one row of 512)
// ---------------------------------------------------------------------------
__device__ __forceinline__ void ln_vals(float v0, float v1,
                                        const float* __restrict__ g,
                                        const float* __restrict__ bb,
                                        float* o0, float* o1, int tid)
{
    float s = v0 + v1, q2 = v0 * v0 + v1 * v1;
#pragma unroll
    for (int o = 32; o; o >>= 1) { s += __shfl_xor(s, o); q2 += __shfl_xor(q2, o); }
    __shared__ float rs[4], rq[4];
    int lane = tid & 63, wid = tid >> 6;
    if (lane == 0) { rs[wid] = s; rq[wid] = q2; }
    __syncthreads();
    s = rs[0] + rs[1] + rs[2] + rs[3];
    q2 = rq[0] + rq[1] + rq[2] + rq[3];
    float mean = s * (1.f / (float)D);
    float var = q2 * (1.f / (float)D) - mean * mean;
    float rstd = rsqrtf(var + 1e-6f);
    *o0 = (v0 - mean) * rstd * g[tid] + bb[tid];
    *o1 = (v1 - mean) * rstd * g[tid + 256] + bb[tid + 256];
}

// plain LN (layer 0 entry): y = bf16(LN(X))
__global__ __launch_bounds__(256) void ln_kernel(const float* __restrict__ x,
                                                 unsigned short* __restrict__ y,
                                                 const float* __restrict__ g,
                                                 const float* __restrict__ bb)
{
    int row = blockIdx.x, tid = threadIdx.x;
    float v0 = x[(size_t)row * D + tid], v1 = x[(size_t)row * D + tid + 256];
    float o0, o1;
    ln_vals(v0, v1, g, bb, &o0, &o1, tid);
    y[(size_t)row * D + tid] = f2bf(o0);
    y[(size_t)row * D + tid + 256] = f2bf(o1);
}

// reduce-LN: xn = X + bias + sum_s P[s]; X = xn; y = bf16(LN(xn))
__global__ __launch_bounds__(256) void lnr_kernel(float* __restrict__ X,
                                                  const float* __restrict__ P,
                                                  const float* __restrict__ bias,
                                                  unsigned short* __restrict__ y,
                                                  const float* __restrict__ g,
                                                  const float* __restrict__ bb)
{
    int row = blockIdx.x, tid = threadIdx.x;
    float v0 = X[(size_t)row * D + tid] + bias[tid];
    float v1 = X[(size_t)row * D + tid + 256] + bias[tid + 256];
#pragma unroll
    for (int s = 0; s < 4; s++) {
        v0 += P[((size_t)s * NT + row) * D + tid];
        v1 += P[((size_t)s * NT + row) * D + tid + 256];
    }
    X[(size_t)row * D + tid] = v0;
    X[(size_t)row * D + tid + 256] = v1;
    float o0, o1;
    ln_vals(v0, v1, g, bb, &o0, &o1, tid);
    y[(size_t)row * D + tid] = f2bf(o0);
    y[(size_t)row * D + tid + 256] = f2bf(o1);
}

// final reduce-LN: out(T,B,D) = LN(X + bias + sum_s P[s])
__global__ __launch_bounds__(256) void final_lnr_kernel(const float* __restrict__ X,
                                                        const float* __restrict__ P,
                                                        const float* __restrict__ bias,
                                                        float* __restrict__ out,
                                                        const float* __restrict__ g,
                                                        const float* __restrict__ bb)
{
    int row = blockIdx.x, tid = threadIdx.x;   // row = b*T + t
    int b = row >> 8, t = row & (T - 1);
    float v0 = X[(size_t)row * D + tid] + bias[tid];
    float v1 = X[(size_t)row * D + tid + 256] + bias[tid + 256];
#pragma unroll
    for (int s = 0; s < 4; s++) {
        v0 += P[((size_t)s * NT + row) * D + tid];
        v1 += P[((size_t)s * NT + row) * D + tid + 256];
    }
    float o0, o1;
    ln_vals(v0, v1, g, bb, &o0, &o1, tid);
    float* op = out + ((size_t)t * B + b) * D;
    op[tid] = o0;
    op[tid + 256] = o1;
}

// ---------------------------------------------------------------------------
// weight f32->bf16 conversion for ALL layers (grid 1548 x L)
// ---------------------------------------------------------------------------
__global__ __launch_bounds__(256) void convert_all_kernel(
    const float* __restrict__ Wq, const float* __restrict__ Wk, const float* __restrict__ Wv,
    const float* __restrict__ Wo, const float* __restrict__ W1, const float* __restrict__ W2,
    const float* __restrict__ bq, const float* __restrict__ bk, const float* __restrict__ bv,
    const float* __restrict__ rel,
    unsigned short* __restrict__ WQKVb, unsigned short* __restrict__ Wob,
    unsigned short* __restrict__ W1b, unsigned short* __restrict__ W2b,
    unsigned short* __restrict__ relb,
    float* __restrict__ bqkv)
{
    int l = blockIdx.y;
    int g = blockIdx.x * 256 + threadIdx.x;   // 0 .. 396287
    const float* src; unsigned short* dst;
    bool zero = false;
    if (g < 98304) {
        int e = g * 8; int piece = e >> 18; int rem = e & 262143;
        src = (piece == 0 ? Wq : piece == 1 ? Wk : Wv) + (size_t)l * 262144 + rem;
        dst = WQKVb + (size_t)l * 786432 + e;
    } else if (g < 131072) {
        int e = (g - 98304) * 8;
        src = Wo + (size_t)l * 262144 + e; dst = Wob + (size_t)l * 262144 + e;
    } else if (g < 262144) {
        int e = (g - 131072) * 8;
        src = W1 + (size_t)l * 1048576 + e; dst = W1b + (size_t)l * 1048576 + e;
    } else if (g < 393216) {
        int e = (g - 262144) * 8;
        src = W2 + (size_t)l * 1048576 + e; dst = W2b + (size_t)l * 1048576 + e;
    } else {
        int e = (g - 393216) * 8;             // 48 x 512 rel table
        int row = e >> 9, cc = e & 511;
        dst = relb + (size_t)l * 24576 + e;
        if (row < BUCKETS + 1) src = rel + ((size_t)l * (BUCKETS + 1) + row) * 512 + cc;
        else { src = nullptr; zero = true; }
    }
    uint4 o;
    if (zero) { o.x = o.y = o.z = o.w = 0u; }
    else {
        float4 x = *(const float4*)src, y = *(const float4*)(src + 4);
        o.x = (unsigned)f2bf(x.x) | ((unsigned)f2bf(x.y) << 16);
        o.y = (unsigned)f2bf(x.z) | ((unsigned)f2bf(x.w) << 16);
        o.z = (unsigned)f2bf(y.x) | ((unsigned)f2bf(y.y) << 16);
        o.w = (unsigned)f2bf(y.z) | ((unsigned)f2bf(y.w) << 16);
    }
    *(uint4*)dst = o;
    if (g < 3 * D) {
        int piece = g >> 9, r2 = g & 511;
        bqkv[l * 1536 + g] = (piece == 0 ? bq : piece == 1 ? bk : bv)[l * 512 + r2];
    }
}

// ---------------------------------------------------------------------------
// bf16 MFMA GEMM (m97 structure): 128x128 tile, BK=32, 4 waves, XOR-swizzled
// ---------------------------------------------------------------------------
template <bool RELU, bool OUTBF16>
__global__ __launch_bounds__(256) void mgemm_kernel(
    const unsigned short* __restrict__ A,
    const unsigned short* __restrict__ W,
    const float* __restrict__ bias,
    void* __restrict__ Cv,
    int N, int M, int K)
{
    __shared__ short smA[2][128 * 32];
    __shared__ short smB[2][128 * 32];
    int tid = threadIdx.x;
    int bn = blockIdx.y * 128;   // output rows
    int bm = blockIdx.x * 128;   // output cols
    const unsigned short* Ab = A + (size_t)bn * K;
    const unsigned short* Wb = W + (size_t)bm * K;

    f32x4 acc[4][4];
#pragma unroll
    for (int i = 0; i < 4; i++)
#pragma unroll
        for (int j = 0; j < 4; j++) acc[i][j] = (f32x4){0.f, 0.f, 0.f, 0.f};

    const int c0 = tid, c1 = tid + 256;
    const int r0 = c0 >> 2, p0 = c0 & 3, l0 = p0 ^ ((r0 >> 1) & 3);
    const int r1 = c1 >> 2, p1 = c1 & 3, l1 = p1 ^ ((r1 >> 1) & 3);

    auto stage = [&](int buf, int k0) {
        stage16(Ab + (size_t)r0 * K + k0 + l0 * 8, &smA[buf][c0 * 8]);
        stage16(Ab + (size_t)r1 * K + k0 + l1 * 8, &smA[buf][c1 * 8]);
        stage16(Wb + (size_t)r0 * K + k0 + l0 * 8, &smB[buf][c0 * 8]);
        stage16(Wb + (size_t)r1 * K + k0 + l1 * 8, &smB[buf][c1 * 8]);
    };

    const int lane = tid & 63;
    const int wv = tid >> 6, wr = wv >> 1, wc = wv & 1;
    int aoff[4], boff[4];
#pragma unroll
    for (int i = 0; i < 4; i++) {
        int ra = wr * 64 + i * 16 + (lane & 15);
        int ca = (lane >> 4) ^ ((ra >> 1) & 3);
        aoff[i] = ra * 32 + ca * 8;
        int rb = wc * 64 + i * 16 + (lane & 15);
        int cb = (lane >> 4) ^ ((rb >> 1) & 3);
        boff[i] = rb * 32 + cb * 8;
    }

    stage(0, 0);
    const int nkt = K >> 5;
    for (int kt = 0; kt < nkt; ++kt) {
        __syncthreads();
        int cur = kt & 1;
        if (kt + 1 < nkt) stage(cur ^ 1, (kt + 1) << 5);
        const short* sa = smA[cur];
        const short* sb = smB[cur];
        bf16x8 af[4], bfr[4];
#pragma unroll
        for (int i = 0; i < 4; i++) af[i] = *(const bf16x8*)(sa + aoff[i]);
#pragma unroll
        for (int j = 0; j < 4; j++) bfr[j] = *(const bf16x8*)(sb + boff[j]);
#pragma unroll
        for (int i = 0; i < 4; i++)
#pragma unroll
            for (int j = 0; j < 4; j++)
                acc[i][j] = __builtin_amdgcn_mfma_f32_16x16x32_bf16(af[i], bfr[j], acc[i][j], 0, 0, 0);
    }

#pragma unroll
    for (int j = 0; j < 4; j++) {
        int col = bm + wc * 64 + j * 16 + (lane & 15);
        float bval = bias[col];
#pragma unroll
        for (int i = 0; i < 4; i++) {
            f32x4 v = acc[i][j];
#pragma unroll
            for (int r = 0; r < 4; r++) {
                int row = bn + wr * 64 + i * 16 + (lane >> 4) * 4 + r;
                float val = v[r] + bval;
                if (RELU) val = fmaxf(val, 0.f);
                if (OUTBF16) ((unsigned short*)Cv)[(size_t)row * M + col] = f2bf(val);
                else         ((float*)Cv)[(size_t)row * M + col] = val;
            }
        }
    }
}

// ---------------------------------------------------------------------------
// split-K bf16 MFMA GEMM: grid (M/128, N/128, S). P[s][n][m] partials, no bias.
// ---------------------------------------------------------------------------
__global__ __launch_bounds__(256) void mgemm_splitk_kernel(
    const unsigned short* __restrict__ A,
    const unsigned short* __restrict__ W,
    float* __restrict__ P,
    int N, int M, int K, int Ksub)
{
    __shared__ short smA[2][128 * 32];
    __shared__ short smB[2][128 * 32];
    int tid = threadIdx.x;
    int s = blockIdx.z;
    int bn = blockIdx.y * 128;
    int bm = blockIdx.x * 128;
    const unsigned short* Ab = A + (size_t)bn * K + s * Ksub;
    const unsigned short* Wb = W + (size_t)bm * K + s * Ksub;

    f32x4 acc[4][4];
#pragma unroll
    for (int i = 0; i < 4; i++)
#pragma unroll
        for (int j = 0; j < 4; j++) acc[i][j] = (f32x4){0.f, 0.f, 0.f, 0.f};

    const int c0 = tid, c1 = tid + 256;
    const int r0 = c0 >> 2, p0 = c0 & 3, l0 = p0 ^ ((r0 >> 1) & 3);
    const int r1 = c1 >> 2, p1 = c1 & 3, l1 = p1 ^ ((r1 >> 1) & 3);

    auto stage = [&](int buf, int k0) {
        stage16(Ab + (size_t)r0 * K + k0 + l0 * 8, &smA[buf][c0 * 8]);
        stage16(Ab + (size_t)r1 * K + k0 + l1 * 8, &smA[buf][c1 * 8]);
        stage16(Wb + (size_t)r0 * K + k0 + l0 * 8, &smB[buf][c0 * 8]);
        stage16(Wb + (size_t)r1 * K + k0 + l1 * 8, &smB[buf][c1 * 8]);
    };

    const int lane = tid & 63;
    const int wv = tid >> 6, wr = wv >> 1, wc = wv & 1;
    int aoff[4], boff[4];
#pragma unroll
    for (int i = 0; i < 4; i++) {
        int ra = wr * 64 + i * 16 + (lane & 15);
        int ca = (lane >> 4) ^ ((ra >> 1) & 3);
        aoff[i] = ra * 32 + ca * 8;
        int rb = wc * 64 + i * 16 + (lane & 15);
        int cb = (lane >> 4) ^ ((rb >> 1) & 3);
        boff[i] = rb * 32 + cb * 8;
    }

    stage(0, 0);
    const int nkt = Ksub >> 5;
    for (int kt = 0; kt < nkt; ++kt) {
        __syncthreads();
        int cur = kt & 1;
        if (kt + 1 < nkt) stage(cur ^ 1, (kt + 1) << 5);
        const short* sa = smA[cur];
        const short* sb = smB[cur];
        bf16x8 af[4], bfr[4];
#pragma unroll
        for (int i = 0; i < 4; i++) af[i] = *(const bf16x8*)(sa + aoff[i]);
#pragma unroll
        for (int j = 0; j < 4; j++) bfr[j] = *(const bf16x8*)(sb + boff[j]);
#pragma unroll
        for (int i = 0; i < 4; i++)
#pragma unroll
            for (int j = 0; j < 4; j++)
                acc[i][j] = __builtin_amdgcn_mfma_f32_16x16x32_bf16(af[i], bfr[j], acc[i][j], 0, 0, 0);
    }

#pragma unroll
    for (int j = 0; j < 4; j++) {
        int col = bm + wc * 64 + j * 16 + (lane & 15);
#pragma unroll
        for (int i = 0; i < 4; i++) {
            f32x4 v = acc[i][j];
#pragma unroll
            for (int r = 0; r < 4; r++) {
                int row = bn + wr * 64 + i * 16 + (lane >> 4) * 4 + r;
                P[((size_t)s * N + row) * M + col] = v[r];
            }
        }
    }
}

// ---------------------------------------------------------------------------
// V transpose: VT[bh][d][ki] = V[b,ki,h*64+d]. grid (64 bh, 4 k-chunks).
// ---------------------------------------------------------------------------
__global__ __launch_bounds__(256) void vtrans_kernel(const unsigned short* __restrict__ qkv,
                                                     unsigned short* __restrict__ vt)
{
    __shared__ unsigned short tile[64 * 66];
    int bh = blockIdx.x, b = bh >> 3, h = bh & 7;
    int kc = blockIdx.y * 64;
    int tid = threadIdx.x;
    int r = tid >> 2, c0 = (tid & 3) * 16;
    const unsigned short* rp = qkv + (size_t)(b * T + kc + r) * QKVLD + 2 * D + h * 64 + c0;
    uint4 w0 = *(const uint4*)rp;
    uint4 w1 = *(const uint4*)(rp + 8);
    unsigned short* tp = &tile[r * 66 + c0];
    unsigned int ww[8] = {w0.x, w0.y, w0.z, w0.w, w1.x, w1.y, w1.z, w1.w};
#pragma unroll
    for (int e = 0; e < 8; e++) {
        tp[2 * e]     = (unsigned short)(ww[e] & 0xffffu);
        tp[2 * e + 1] = (unsigned short)(ww[e] >> 16);
    }
    __syncthreads();
    int d = tid >> 2, k0 = (tid & 3) * 16;
    unsigned int outw[8];
#pragma unroll
    for (int i = 0; i < 8; i++) {
        unsigned int lo = tile[(k0 + 2 * i) * 66 + d];
        unsigned int hi = tile[(k0 + 2 * i + 1) * 66 + d];
        outw[i] = lo | (hi << 16);
    }
    unsigned short* op = vt + (size_t)(bh * 64 + d) * 256 + kc + k0;
    *(uint4*)op = *(uint4*)&outw[0];
    *(uint4*)(op + 8) = *(uint4*)&outw[4];
}

// ---------------------------------------------------------------------------
// Fused MFMA attention (unchanged from round 4)
// ---------------------------------------------------------------------------
__global__ __launch_bounds__(256) void fattn_kernel(
    const unsigned short* __restrict__ qkv,
    const unsigned short* __restrict__ vt,
    const unsigned short* __restrict__ relb,
    const float* __restrict__ uvec,
    const float* __restrict__ vvec,
    const int* __restrict__ dist,
    const int* __restrict__ lengths,
    unsigned short* __restrict__ ctx)
{
    __shared__ unsigned short Ps[4][16][256];
    __shared__ float Qrel[4][16][49];

    int bh = blockIdx.x, b = bh >> 3, h = bh & 7;
    int qi0 = blockIdx.y * 64;
    int tid = threadIdx.x, w = tid >> 6, lane = tid & 63;
    int l15 = lane & 15, g = lane >> 4;
    int qr = qi0 + w * 16;

    const unsigned short* qbase = qkv + (size_t)(b * T + qr + l15) * QKVLD + h * 64 + g * 8;
    bf16x8 qa0 = *(const bf16x8*)(qbase);
    bf16x8 qa1 = *(const bf16x8*)(qbase + 32);

    bf16x8 qu0, qu1;
    {
        const float* up = uvec + h * 64 + g * 8;
        float ua0[8], ua1[8];
        *(float4*)&ua0[0] = *(const float4*)(up);
        *(float4*)&ua0[4] = *(const float4*)(up + 4);
        *(float4*)&ua1[0] = *(const float4*)(up + 32);
        *(float4*)&ua1[4] = *(const float4*)(up + 36);
#pragma unroll
        for (int e = 0; e < 8; e++) {
            qu0[e] = (short)f2bf(0.125f * bf2f((unsigned short)qa0[e]) + ua0[e]);
            qu1[e] = (short)f2bf(0.125f * bf2f((unsigned short)qa1[e]) + ua1[e]);
        }
    }

    {
        const float* vp = vvec + h * 64 + g * 8;
        float va0[8], va1[8];
        *(float4*)&va0[0] = *(const float4*)(vp);
        *(float4*)&va0[4] = *(const float4*)(vp + 4);
        *(float4*)&va1[0] = *(const float4*)(vp + 32);
        *(float4*)&va1[4] = *(const float4*)(vp + 36);
        bf16x8 qh0, qh1;
#pragma unroll
        for (int e = 0; e < 8; e++) {
            qh0[e] = (short)f2bf(0.125f * bf2f((unsigned short)qa0[e]) + va0[e]);
            qh1[e] = (short)f2bf(0.125f * bf2f((unsigned short)qa1[e]) + va1[e]);
        }
        f32x4 qacc[3];
#pragma unroll
        for (int j = 0; j < 3; j++) qacc[j] = (f32x4){0.f, 0.f, 0.f, 0.f};
#pragma unroll
        for (int j = 0; j < 3; j++) {
            const unsigned short* rp = relb + (size_t)(j * 16 + l15) * 512 + h * 64 + g * 8;
            bf16x8 r0 = *(const bf16x8*)(rp);
            bf16x8 r1 = *(const bf16x8*)(rp + 32);
            qacc[j] = __builtin_amdgcn_mfma_f32_16x16x32_bf16(qh0, r0, qacc[j], 0, 0, 0);
            qacc[j] = __builtin_amdgcn_mfma_f32_16x16x32_bf16(qh1, r1, qacc[j], 0, 0, 0);
        }
#pragma unroll
        for (int j = 0; j < 3; j++)
#pragma unroll
            for (int r = 0; r < 4; r++)
                Qrel[w][g * 4 + r][j * 16 + l15] = qacc[j][r];
    }

    f32x4 acc[16];
#pragma unroll
    for (int j = 0; j < 16; j++) acc[j] = (f32x4){0.f, 0.f, 0.f, 0.f};
    const unsigned short* kbase = qkv + (size_t)(b * T) * QKVLD + 512 + h * 64 + g * 8;
#pragma unroll
    for (int j = 0; j < 16; j++) {
        const unsigned short* kp = kbase + (size_t)(j * 16 + l15) * QKVLD;
        bf16x8 k0 = *(const bf16x8*)(kp);
        bf16x8 k1 = *(const bf16x8*)(kp + 32);
        acc[j] = __builtin_amdgcn_mfma_f32_16x16x32_bf16(qu0, k0, acc[j], 0, 0, 0);
        acc[j] = __builtin_amdgcn_mfma_f32_16x16x32_bf16(qu1, k1, acc[j], 0, 0, 0);
    }

    int len = lengths[b];
    float rinv[4];
    const int* db = dist + (size_t)b * T * T;
#pragma unroll
    for (int r = 0; r < 4; r++) {
        int rowloc = g * 4 + r;
        int qrow = qr + rowloc;
        const int* dpr = db + (size_t)qrow * T;
        float m = -3.0e38f;
#pragma unroll
        for (int j = 0; j < 16; j++) {
            int ki = j * 16 + l15;
            int dv = dpr[ki];
            float s = acc[j][r] + Qrel[w][rowloc][dv];
            s = (ki < len) ? s : -1.0e30f;
            acc[j][r] = s;
            m = fmaxf(m, s);
        }
#pragma unroll
        for (int o = 8; o; o >>= 1) m = fmaxf(m, __shfl_xor(m, o));
        float sum = 0.f;
#pragma unroll
        for (int j = 0; j < 16; j++) {
            int ki = j * 16 + l15;
            float p = __expf(acc[j][r] - m);
            sum += p;
            int cph = ((ki >> 3) ^ (rowloc & 7));
            Ps[w][rowloc][cph * 8 + (ki & 7)] = f2bf(p);
        }
#pragma unroll
        for (int o = 8; o; o >>= 1) sum += __shfl_xor(sum, o);
        rinv[r] = 1.0f / sum;
    }

    f32x4 oacc[4];
#pragma unroll
    for (int j = 0; j < 4; j++) oacc[j] = (f32x4){0.f, 0.f, 0.f, 0.f};
    const unsigned short* vtb = vt + (size_t)bh * 64 * 256;
#pragma unroll
    for (int ks = 0; ks < 8; ks++) {
        int c = ks * 4 + g;
        int cph = c ^ (l15 & 7);
        bf16x8 pa = *(const bf16x8*)&Ps[w][l15][cph * 8];
#pragma unroll
        for (int j2 = 0; j2 < 4; j2++) {
            bf16x8 vb = *(const bf16x8*)(vtb + (size_t)(j2 * 16 + l15) * 256 + c * 8);
            oacc[j2] = __builtin_amdgcn_mfma_f32_16x16x32_bf16(pa, vb, oacc[j2], 0, 0, 0);
        }
    }

#pragma unroll
    for (int j2 = 0; j2 < 4; j2++) {
#pragma unroll
        for (int r = 0; r < 4; r++) {
            int qrow = qr + g * 4 + r;
            int dcol = j2 * 16 + l15;
            ctx[(size_t)(b * T + qrow) * D + h * 64 + dcol] = f2bf(oacc[j2][r] * rinv[r]);
        }
    }
}

// ---------------------------------------------------------------------------
extern "C" void kernel_launch(void* const* d_in, const int* in_sizes, int n_in,
                              void* d_out, int out_size, void* d_ws, size_t ws_size,
                              hipStream_t stream)
{
    const float* src     = (const float*)d_in[0];
    const int*   lengths = (const int*)d_in[1];
    const int*   dist    = (const int*)d_in[2];
    const float* u       = (const float*)d_in[3];
    const float* v       = (const float*)d_in[4];
    const float* ln1_g   = (const float*)d_in[5];
    const float* ln1_b   = (const float*)d_in[6];
    const float* Wq      = (const float*)d_in[7];
    const float* Wk      = (const float*)d_in[8];
    const float* Wv      = (const float*)d_in[9];
    const float* Wo      = (const float*)d_in[10];
    const float* bq      = (const float*)d_in[11];
    const float* bk      = (const float*)d_in[12];
    const float* bv      = (const float*)d_in[13];
    const float* bo      = (const float*)d_in[14];
    const float* rel     = (const float*)d_in[15];
    const float* fg      = (const float*)d_in[16];
    const float* fb      = (const float*)d_in[17];
    const float* W1      = (const float*)d_in[18];
    const float* b1      = (const float*)d_in[19];
    const float* W2      = (const float*)d_in[20];
    const float* b2      = (const float*)d_in[21];
    const float* flg     = (const float*)d_in[22];
    const float* flb     = (const float*)d_in[23];

    float* ws = (float*)d_ws;
    float*          X     = ws;                                   // [0, 1048576)
    unsigned short* QKVb  = (unsigned short*)(ws + 1048576);      // 3145728 bf16
    unsigned short* Hb    = (unsigned short*)(ws + 2621440);      // 1048576 bf16
    unsigned short* CTX   = (unsigned short*)(ws + 3145728);      // 1048576 bf16
    unsigned short* FF1   = (unsigned short*)(ws + 3670016);      // 4194304 bf16
    unsigned short* VT    = (unsigned short*)(ws + 5767168);      // 1048576 bf16
    float*          Pbuf  = ws + 6291456;                         // 4x2048x512 f32
    unsigned short* WQKVb = (unsigned short*)(ws + 10485760);     // 4x786432 bf16
    unsigned short* Wob   = (unsigned short*)(ws + 12058624);     // 4x262144 bf16
    unsigned short* W1b   = (unsigned short*)(ws + 12582912);     // 4x1048576 bf16
    unsigned short* W2b   = (unsigned short*)(ws + 14680064);     // 4x1048576 bf16
    unsigned short* RELb  = (unsigned short*)(ws + 16777216);     // 4x24576 bf16
    float*          bqkv  = ws + 16826368;                        // 4x1536 f

    embed_kernel<<<T, 256, 0, stream>>>(src, X);

    convert_all_kernel<<<dim3(1548, L), 256, 0, stream>>>(
        Wq, Wk, Wv, Wo, W1, W2, bq, bk, bv, rel,
        WQKVb, Wob, W1b, W2b, RELb, bqkv);

    for (int l = 0; l < L; l++) {
        const unsigned short* wqkv = WQKVb + (size_t)l * 786432;
        const unsigned short* wob  = Wob   + (size_t)l * 262144;
        const unsigned short* w1b  = W1b   + (size_t)l * 1048576;
        const unsigned short* w2b  = W2b   + (size_t)l * 1048576;
        const unsigned short* relb = RELb  + (size_t)l * 24576;
        const float*          bql  = bqkv  + (size_t)l * 1536;

        // entry LN: for l>0 also reduces the previous layer's FFN2 partials
        if (l == 0)
            ln_kernel<<<NT, 256, 0, stream>>>(X, Hb, ln1_g, ln1_b);
        else
            lnr_kernel<<<NT, 256, 0, stream>>>(X, Pbuf, b2 + (size_t)(l - 1) * D,
                                               Hb, ln1_g + l * D, ln1_b + l * D);

        mgemm_kernel<false, true><<<dim3(12, 16), 256, 0, stream>>>(
            Hb, wqkv, bql, QKVb, NT, QKVLD, D);

        vtrans_kernel<<<dim3(64, 4), 256, 0, stream>>>(QKVb, VT);

        fattn_kernel<<<dim3(B * H, T / 64), 256, 0, stream>>>(
            QKVb, VT, relb, u, v, dist, lengths, CTX);

        // Wo split-K -> partials
        mgemm_splitk_kernel<<<dim3(4, 16, 4), 256, 0, stream>>>(
            CTX, wob, Pbuf, NT, D, D, D / 4);

        // ln2 reduces Wo partials (+bo +X residual), writes X and Hb
        lnr_kernel<<<NT, 256, 0, stream>>>(X, Pbuf, bo + (size_t)l * D,
                                           Hb, fg + l * D, fb + l * D);

        mgemm_kernel<true, true><<<dim3(16, 16), 256, 0, stream>>>(
            Hb, w1b, b1 + (size_t)l * DFF, FF1, NT, DFF, D);

        // FFN2 split-K -> partials (reduced by next layer's entry LN / final LN)
        mgemm_splitk_kernel<<<dim3(4, 16, 4), 256, 0, stream>>>(
            FF1, w2b, Pbuf, NT, D, DFF, DFF / 4);
    }

    final_lnr_kernel<<<NT, 256, 0, stream>>>(X, Pbuf, b2 + (size_t)(L - 1) * D,
                                             (float*)d_out, flg, flb);
}